// Round 11
// baseline (194.083 us; speedup 1.0000x reference)
//
#include <hip/hip_runtime.h>
#include <math.h>

typedef float f32x4 __attribute__((ext_vector_type(4)));
typedef short s16x8 __attribute__((ext_vector_type(8)));
typedef short s16x4 __attribute__((ext_vector_type(4)));
typedef unsigned u32x4 __attribute__((ext_vector_type(4)));

__device__ __forceinline__ short f2bf(float f) {
    unsigned u = __builtin_bit_cast(unsigned, f);
    unsigned r = u + 0x7FFFu + ((u >> 16) & 1u);
    return (short)(r >> 16);
}
__device__ __forceinline__ float bf2f(short h) {
    return __builtin_bit_cast(float, ((unsigned)(unsigned short)h) << 16);
}
__device__ __forceinline__ unsigned pack2(short a, short b) {
    return (unsigned)(unsigned short)a | ((unsigned)(unsigned short)b << 16);
}
// packed f32x2 -> bf16x2, RTNE (same rounding as f2bf); low = a, high = b
__device__ __forceinline__ unsigned cvtpk(float a, float b) {
    unsigned r;
    asm("v_cvt_pk_bf16_f32 %0, %1, %2" : "=v"(r) : "v"(a), "v"(b));
    return r;
}

__device__ __forceinline__ void split16v(const float* __restrict__ p,
                                         short* __restrict__ h,
                                         short* __restrict__ l) {
    f32x4 a0 = *(const f32x4*)(p);
    f32x4 a1 = *(const f32x4*)(p + 4);
    f32x4 a2 = *(const f32x4*)(p + 8);
    f32x4 a3 = *(const f32x4*)(p + 12);
    #pragma unroll
    for (int i = 0; i < 4; ++i) {
        short t0;
        t0 = f2bf(a0[i]); h[i]      = t0; l[i]      = f2bf(a0[i] - bf2f(t0));
        t0 = f2bf(a1[i]); h[4 + i]  = t0; l[4 + i]  = f2bf(a1[i] - bf2f(t0));
        t0 = f2bf(a2[i]); h[8 + i]  = t0; l[8 + i]  = f2bf(a2[i] - bf2f(t0));
        t0 = f2bf(a3[i]); h[12 + i] = t0; l[12 + i] = f2bf(a3[i] - bf2f(t0));
    }
}

__device__ __forceinline__ void gload16(const void* g, void* l) {
    __builtin_amdgcn_global_load_lds(
        (const __attribute__((address_space(1))) unsigned int*)g,
        (__attribute__((address_space(3))) unsigned int*)l,
        16, 0, 0);
}

// decay constants for head h (shared by chunk + finish kernels)
__device__ __forceinline__ void decay_params(int h, int n0, float& l2g, int& stLo) {
    float lg0 = logf(1.0f / 32.0f), lg1 = logf(1.0f / 512.0f);
    float om = expf(lg0 + (float)h * (lg1 - lg0) * (1.0f / 7.0f));  // 1-gamma
    l2g = log2f(1.0f - om);
    int Dcut = (int)(11.5129255f / om) + 64;
    stLo = (n0 - Dcut) >> 6;
    if (stLo < 0) stLo = 0;
}

// ---------------------------------------------------------------------------
// Pre-split WEIGHTS ONLY into hi/lo bf16 + rotary cos/sin table.
// ---------------------------------------------------------------------------
__global__ __launch_bounds__(256) void presplit_kernel(
    const float* __restrict__ W0, const float* __restrict__ W1,
    const float* __restrict__ W2, const float* __restrict__ W3,
    const float* __restrict__ W4,
    short* __restrict__ Wsp, float2* __restrict__ SC)
{
    const int blk = blockIdx.x;
    const int t = threadIdx.x;
    short hbuf[16], lbuf[16];
    if (blk < 256) {
        const int w = blk >> 6, bi = blk & 63;
        const float* src = (w == 0) ? W0 : (w == 1) ? W1 : (w == 2) ? W2 : W3;
        const int idx = (bi * 256 + t) * 16;
        const int row = idx >> 9, k0 = idx & 511;
        const int ntile = row >> 7, r = row & 127;
        const int kstep = k0 >> 5, kk0 = k0 & 31;
        const int s = (r & 3) << 4;
        split16v(src + idx, hbuf, lbuf);
        short* hp = Wsp + (long)w * 524288 + (ntile * 16 + kstep) * 8192 + r * 32;
        short* lp = hp + 4096;
        const int oA = ((2 * kk0) ^ s) >> 1;
        const int oB = ((2 * kk0 + 16) ^ s) >> 1;
        *(s16x8*)(hp + oA) = *(s16x8*)(hbuf);
        *(s16x8*)(hp + oB) = *(s16x8*)(hbuf + 8);
        *(s16x8*)(lp + oA) = *(s16x8*)(lbuf);
        *(s16x8*)(lp + oB) = *(s16x8*)(lbuf + 8);
    } else if (blk < 320) {
        const int bi = blk - 256;
        const int idx = (bi * 256 + t) * 16;
        short* hi = Wsp + (long)4 * 524288;
        short* lo = hi + 262144;
        split16v(W4 + idx, hbuf, lbuf);
        *(s16x8*)(hi + idx)     = *(s16x8*)(hbuf);
        *(s16x8*)(hi + idx + 8) = *(s16x8*)(hbuf + 8);
        *(s16x8*)(lo + idx)     = *(s16x8*)(lbuf);
        *(s16x8*)(lo + idx + 8) = *(s16x8*)(lbuf + 8);
    } else {
        // rotary table: gid = pos*32 + pp
        const int gid = (blk - 320) * 256 + t;
        const int pos = gid >> 5, pp = gid & 31;
        const float theta = powf(10000.0f, -(float)pp * (1.0f / 31.0f));
        const float ang = (float)pos * theta;
        SC[gid] = make_float2(cosf(ang), sinf(ang));
    }
}

// ---------------------------------------------------------------------------
// Fused Q/K/V/G projections. 64x128 tile, 8 waves (512 thr) 2x4, BK=32.
// Triple-buffered global_load_lds staging (3 x 24 KB), counted vmcnt(3),
// raw s_barrier, XCD-locality remap, s_setprio around MFMA cluster.
// X staged as RAW fp32 (per-lane swizzled global source); hi/lo bf16 split
// in-register via v_cvt_pk_bf16_f32. Stage layout: [X fp32 8K | Wh 8K | Wl 8K].
// ---------------------------------------------------------------------------
__global__ __launch_bounds__(512, 4) void projqkvg_kernel(
    const float* __restrict__ X0, const float* __restrict__ X1,
    const float* __restrict__ X2, const short* __restrict__ Wsp,
    const float* __restrict__ bq, const float* __restrict__ bk,
    const float* __restrict__ bv, const float* __restrict__ bg,
    const float2* __restrict__ SC,
    short* __restrict__ Qh, short* __restrict__ Ql,
    short* __restrict__ Kh, short* __restrict__ Vth,
    float* __restrict__ G)
{
    __shared__ __align__(16) short SB[36864];   // 72 KB = 3 stages x 24 KB

    const int fid = blockIdx.x + 4 * (blockIdx.y + 64 * blockIdx.z);
    const int mtile = fid & 63;
    const int rr = fid >> 6;            // 0..15
    const int mode = rr & 3;
    const int ntile = rr >> 2;
    const int m0 = mtile * 64, n0 = ntile * 128;

    const int xi = (mode == 1) ? 1 : (mode == 2) ? 2 : 0;
    const float* Xf = (xi == 0) ? X0 : (xi == 1) ? X1 : X2;
    const float* bias = (mode == 0) ? bq : (mode == 1) ? bk
                       : (mode == 2) ? bv : bg;

    const int t = threadIdx.x, lane = t & 63, wv = t >> 6;   // 8 waves
    const int wm = wv >> 2, wn = wv & 3;                      // 2 x 4
    const int quad = lane >> 4, l15 = lane & 15;

    const short* Wblk = Wsp + (long)mode * 524288 + (long)ntile * 16 * 8192;

    // staging: 24 chunks of 1 KB; wave wv owns chunks wv*3 .. wv*3+2
    // chunks 0-7: X fp32 (per-lane swizzled source); 8-23: W hi/lo bf16
    const int c0 = wv * 3;
    const char* gs[3];
    int gstp[3];
    #pragma unroll
    for (int i = 0; i < 3; ++i) {
        const int c = c0 + i;
        if (c < 8) {
            const int u = c * 64 + lane;        // LDS unit = row*8 + ucol
            const int row = u >> 3, ucol = u & 7;
            gs[i] = (const char*)(Xf + (long)(m0 + row) * 512)
                    + ((ucol ^ (row & 7)) << 4);
            gstp[i] = 128;                      // 32 floats per K-step
        } else {
            gs[i] = (const char*)(Wblk + (c - 8) * 512 + lane * 8);
            gstp[i] = 16384;                    // 8192 shorts per K-step
        }
    }

    auto STAGE = [&](int stg, int ks) {
        char* dstb = (char*)SB + stg * 24576 + c0 * 1024;
        #pragma unroll
        for (int i = 0; i < 3; ++i)
            gload16(gs[i] + (long)ks * gstp[i], dstb + i * 1024);
    };

    // fragment LDS byte offsets (K-step invariant)
    int aoff[2];
    #pragma unroll
    for (int s2 = 0; s2 < 2; ++s2) {
        const int row = wm * 32 + s2 * 16 + l15;
        aoff[s2] = row * 128 + ((quad * 32) ^ ((row & 7) << 4));
    }
    const int sxw = (l15 & 3) << 4;
    int boff[2];
    #pragma unroll
    for (int s2 = 0; s2 < 2; ++s2)
        boff[s2] = 8192 + (wn * 32 + s2 * 16 + l15) * 64 + ((quad * 16) ^ sxw);

    f32x4 acc[2][2];
    #pragma unroll
    for (int i = 0; i < 2; ++i)
        #pragma unroll
        for (int j = 0; j < 2; ++j)
            acc[i][j] = (f32x4){0.f, 0.f, 0.f, 0.f};

    // prologue: fill stages 0 and 1; wait only for stage 0 (oldest 3)
    STAGE(0, 0);
    STAGE(1, 1);
    asm volatile("s_waitcnt vmcnt(3)" ::: "memory");
    __builtin_amdgcn_s_barrier();

    int cur = 0;
    for (int ks = 0; ks < 16; ++ks) {
        if (ks < 14) {
            int fill = cur + 2; if (fill >= 3) fill -= 3;
            STAGE(fill, ks + 2);
        }
        __builtin_amdgcn_sched_barrier(0);

        const char* stg = (const char*)SB + cur * 24576;
        s16x8 ah[2], al[2], bh[2], bl[2];
        #pragma unroll
        for (int s2 = 0; s2 < 2; ++s2) {
            f32x4 x0 = *(const f32x4*)(stg + aoff[s2]);
            f32x4 x1 = *(const f32x4*)(stg + (aoff[s2] ^ 16));
            u32x4 hv, lv;
            #pragma unroll
            for (int j = 0; j < 2; ++j) {
                float a0 = x0[2 * j], b0 = x0[2 * j + 1];
                float a1 = x1[2 * j], b1 = x1[2 * j + 1];
                unsigned h0 = cvtpk(a0, b0);
                unsigned h1 = cvtpk(a1, b1);
                hv[j]     = h0;
                hv[2 + j] = h1;
                float fa0 = __builtin_bit_cast(float, h0 << 16);
                float fb0 = __builtin_bit_cast(float, h0 & 0xFFFF0000u);
                float fa1 = __builtin_bit_cast(float, h1 << 16);
                float fb1 = __builtin_bit_cast(float, h1 & 0xFFFF0000u);
                lv[j]     = cvtpk(a0 - fa0, b0 - fb0);
                lv[2 + j] = cvtpk(a1 - fa1, b1 - fb1);
            }
            ah[s2] = __builtin_bit_cast(s16x8, hv);
            al[s2] = __builtin_bit_cast(s16x8, lv);
        }
        #pragma unroll
        for (int s2 = 0; s2 < 2; ++s2) {
            bh[s2] = *(const s16x8*)(stg + boff[s2]);
            bl[s2] = *(const s16x8*)(stg + 8192 + boff[s2]);
        }
        __builtin_amdgcn_s_setprio(1);
        #pragma unroll
        for (int i = 0; i < 2; ++i)
            #pragma unroll
            for (int j = 0; j < 2; ++j) {
                acc[i][j] = __builtin_amdgcn_mfma_f32_16x16x32_bf16(ah[i], bh[j], acc[i][j], 0, 0, 0);
                acc[i][j] = __builtin_amdgcn_mfma_f32_16x16x32_bf16(al[i], bh[j], acc[i][j], 0, 0, 0);
                acc[i][j] = __builtin_amdgcn_mfma_f32_16x16x32_bf16(ah[i], bl[j], acc[i][j], 0, 0, 0);
            }
        __builtin_amdgcn_s_setprio(0);

        if (ks < 14)       asm volatile("s_waitcnt vmcnt(3)" ::: "memory");
        else if (ks == 14) asm volatile("s_waitcnt vmcnt(0)" ::: "memory");
        __builtin_amdgcn_sched_barrier(0);
        __builtin_amdgcn_s_barrier();

        cur += 1; if (cur >= 3) cur -= 3;
    }

    __syncthreads();   // full drain; LDS reusable by epilogues

    const int bb = m0 >> 11, posb = m0 & 2047;

    if (mode == 0) {
        short* Thi = SB + wv * 1280;            // 16 x 40
        short* Tlo = Thi + 640;
        const int head = (n0 >> 6) + (wn >> 1);
        const int dbase = (wn & 1) * 32;
        #pragma unroll
        for (int ms = 0; ms < 2; ++ms) {
            #pragma unroll
            for (int ns = 0; ns < 2; ++ns) {
                const int col = n0 + wn * 32 + ns * 16 + l15;
                const float bvv = bias[col];
                const int pp = (col & 63) >> 1;
                #pragma unroll
                for (int r = 0; r < 4; ++r) {
                    const int m = m0 + wm * 32 + ms * 16 + quad * 4 + r;
                    const int pos = m & 2047;
                    float x = acc[ms][ns][r] + bvv;
                    float prt = __shfl_xor(x, 1);
                    float2 sc = SC[pos * 32 + pp];
                    float y0 = x * sc.x - prt * sc.y;
                    float y1 = prt * sc.x + x * sc.y;
                    if (!(l15 & 1)) {
                        short h0 = f2bf(y0), h1 = f2bf(y1);
                        short l0 = f2bf(y0 - bf2f(h0)), l1 = f2bf(y1 - bf2f(h1));
                        const int o = (quad * 4 + r) * 40 + ns * 16 + l15;
                        *(unsigned*)&Thi[o] = pack2(h0, h1);
                        *(unsigned*)&Tlo[o] = pack2(l0, l1);
                    }
                }
            }
            const int mrow = wm * 32 + ms * 16;
            const int row = lane >> 2, ch = (lane & 3) * 8;
            s16x8 vh = *(const s16x8*)&Thi[row * 40 + ch];
            s16x8 vl = *(const s16x8*)&Tlo[row * 40 + ch];
            const long o = ((long)(bb * 8 + head) * 2048 + posb + mrow + row) * 64 + dbase + ch;
            *(s16x8*)(Qh + o) = vh;
            *(s16x8*)(Ql + o) = vl;
        }
    } else if (mode == 1) {
        short* Thi = SB + wv * 640;             // 16 x 40
        const int head = (n0 >> 6) + (wn >> 1);
        const int dbase = (wn & 1) * 32;
        #pragma unroll
        for (int ms = 0; ms < 2; ++ms) {
            #pragma unroll
            for (int ns = 0; ns < 2; ++ns) {
                const int col = n0 + wn * 32 + ns * 16 + l15;
                const float bvv = bias[col];
                const int pp = (col & 63) >> 1;
                #pragma unroll
                for (int r = 0; r < 4; ++r) {
                    const int m = m0 + wm * 32 + ms * 16 + quad * 4 + r;
                    const int pos = m & 2047;
                    float x = acc[ms][ns][r] + bvv;
                    float prt = __shfl_xor(x, 1);
                    float2 sc = SC[pos * 32 + pp];
                    float y0 = (x * sc.x - prt * sc.y) * 0.125f;
                    float y1 = (prt * sc.x + x * sc.y) * 0.125f;
                    if (!(l15 & 1)) {
                        const int o = (quad * 4 + r) * 40 + ns * 16 + l15;
                        *(unsigned*)&Thi[o] = pack2(f2bf(y0), f2bf(y1));
                    }
                }
            }
            const int mrow = wm * 32 + ms * 16;
            const int row = lane >> 2, ch = (lane & 3) * 8;
            s16x8 vh = *(const s16x8*)&Thi[row * 40 + ch];
            const long o = ((long)(bb * 8 + head) * 2048 + posb + mrow + row) * 64 + dbase + ch;
            *(s16x8*)(Kh + o) = vh;
        }
    } else if (mode == 2) {
        short* T2 = SB;   // 128 x 72
        #pragma unroll
        for (int ns = 0; ns < 2; ++ns) {
            const int col = n0 + wn * 32 + ns * 16 + l15;
            const float bvv = bias[col];
            #pragma unroll
            for (int ms = 0; ms < 2; ++ms) {
                s16x4 pk;
                #pragma unroll
                for (int r = 0; r < 4; ++r)
                    pk[r] = f2bf(acc[ms][ns][r] + bvv);
                *(s16x4*)&T2[(wn * 32 + ns * 16 + l15) * 72
                             + wm * 32 + ms * 16 + quad * 4] = pk;
            }
        }
        __syncthreads();
        #pragma unroll
        for (int pass = 0; pass < 2; ++pass) {
            const int row = pass * 64 + (t >> 3);    // 0..127
            const int ch = (t & 7) * 8;
            s16x8 v = *(const s16x8*)&T2[row * 72 + ch];
            const int head = (n0 >> 6) + (row >> 6);
            const int d = row & 63;
            const long o = ((long)(bb * 8 + head) * 64 + d) * 2048 + posb + ch;
            *(s16x8*)(Vth + o) = v;
        }
    } else {
        #pragma unroll
        for (int ns = 0; ns < 2; ++ns) {
            const int col = n0 + wn * 32 + ns * 16 + l15;
            const float bvv = bias[col];
            #pragma unroll
            for (int ms = 0; ms < 2; ++ms)
                #pragma unroll
                for (int r = 0; r < 4; ++r) {
                    const int m = m0 + wm * 32 + ms * 16 + quad * 4 + r;
                    float x = acc[ms][ns][r] + bvv;
                    G[(long)m * 512 + col] = x / (1.0f + expf(-x));
                }
        }
    }
}

// ---------------------------------------------------------------------------
// Retention attention, split-K with CHUNK=8 (grid bh x qt x c, c<4),
// double-buffered K/V LDS, ONE barrier/tile. Single-chunk pairs (c==0 &&
// ntiles<=8) run the groupnorm/gate/store epilogue inline; else partials
// go to Racc (4 slices/pair).
// ---------------------------------------------------------------------------
__global__ __launch_bounds__(256) void attn_chunk_kernel(
    const short* __restrict__ Qh_g, const short* __restrict__ Ql_g,
    const short* __restrict__ Kh_g, const short* __restrict__ Vth_g,
    const float* __restrict__ G, short* __restrict__ RGh,
    float* __restrict__ Racc)
{
    __shared__ __align__(16) short KhS[2][4608], VhS[2][4608];
    __shared__ __align__(16) short PhS[4352];

    const int fid = blockIdx.x;          // 0..2047
    const int bh = fid & 15;
    const int rest = fid >> 4;
    const int qt = rest & 31;
    const int c  = rest >> 5;            // 0..3
    const int h = bh & 7, b = bh >> 3;
    const int n0 = qt * 64;

    float l2g;
    int stLo;
    decay_params(h, n0, l2g, stLo);
    const int ntiles = qt - stLo + 1;
    const int st0 = stLo + c * 8;
    if (st0 > qt) return;
    const int stHi = min(st0 + 7, qt);

    const int t = threadIdx.x, lane = t & 63, wv = t >> 6;
    const int quad = lane >> 4, l15 = lane & 15;
    const long base = (long)bh * 2048 * 64;

    float gneg[16];
    #pragma unroll
    for (int i = 0; i < 16; ++i)
        gneg[i] = exp2f(-(float)((i >> 2) * 16 + (i & 3)) * l2g);

    const int srow = t >> 2;
    const int scol = (t & 3) * 16;
    const int n = n0 + wv * 16 + l15;

    s16x8 qh[2], ql[2];
    {
        const short* qp  = Qh_g + base + (long)(n0 + wv * 16 + l15) * 64 + quad * 8;
        const short* qp2 = Ql_g + base + (long)(n0 + wv * 16 + l15) * 64 + quad * 8;
        qh[0] = *(const s16x8*)qp;
        qh[1] = *(const s16x8*)(qp + 32);
        ql[0] = *(const s16x8*)qp2;
        ql[1] = *(const s16x8*)(qp2 + 32);
    }

    f32x4 racc[4];
    #pragma unroll
    for (int i = 0; i < 4; ++i) racc[i] = (f32x4){0.f, 0.f, 0.f, 0.f};

    // prologue: load tile st0 and write buffer 0
    s16x8 pk0, pk1, pv0, pv1;
    {
        const long ko = base + (long)(st0 * 64 + srow) * 64 + scol;
        pk0 = *(const s16x8*)(Kh_g + ko);
        pk1 = *(const s16x8*)(Kh_g + ko + 8);
        const long vo = base + (long)srow * 2048 + st0 * 64 + scol;
        pv0 = *(const s16x8*)(Vth_g + vo);
        pv1 = *(const s16x8*)(Vth_g + vo + 8);
    }
    *(s16x8*)&KhS[0][srow * 72 + scol]     = pk0;
    *(s16x8*)&KhS[0][srow * 72 + scol + 8] = pk1;
    *(s16x8*)&VhS[0][srow * 72 + scol]     = pv0;
    *(s16x8*)&VhS[0][srow * 72 + scol + 8] = pv1;
    __syncthreads();

    int cur = 0;
    for (int st = st0; st <= stHi; ++st, cur ^= 1) {
        if (st < stHi) {
            const long ko = base + (long)((st + 1) * 64 + srow) * 64 + scol;
            pk0 = *(const s16x8*)(Kh_g + ko);
            pk1 = *(const s16x8*)(Kh_g + ko + 8);
            const long vo = base + (long)srow * 2048 + (st + 1) * 64 + scol;
            pv0 = *(const s16x8*)(Vth_g + vo);
            pv1 = *(const s16x8*)(Vth_g + vo + 8);
        }

        const short* khs = KhS[cur];
        const short* vhs = VhS[cur];
        const int s0 = st * 64;
        const float t0 = exp2f((float)(n - s0 - quad * 4) * l2g);

        #pragma unroll
        for (int sub = 0; sub < 4; ++sub) {
            const int ro = (sub * 16 + l15) * 72 + quad * 8;
            s16x8 kh0 = *(const s16x8*)&khs[ro];
            s16x8 kh1 = *(const s16x8*)&khs[ro + 32];
            f32x4 sacc = (f32x4){0.f, 0.f, 0.f, 0.f};
            sacc = __builtin_amdgcn_mfma_f32_16x16x32_bf16(kh0, qh[0], sacc, 0, 0, 0);
            sacc = __builtin_amdgcn_mfma_f32_16x16x32_bf16(kh1, qh[1], sacc, 0, 0, 0);
            sacc = __builtin_amdgcn_mfma_f32_16x16x32_bf16(kh0, ql[0], sacc, 0, 0, 0);
            sacc = __builtin_amdgcn_mfma_f32_16x16x32_bf16(kh1, ql[1], sacc, 0, 0, 0);

            const int sb = s0 + sub * 16 + quad * 4;
            s16x4 pkh;
            #pragma unroll
            for (int r = 0; r < 4; ++r) {
                const int s = sb + r;
                const float wgt = (n >= s) ? t0 * gneg[sub * 4 + r] : 0.0f;
                pkh[r] = f2bf(sacc[r] * wgt);
            }
            *(s16x4*)&PhS[(wv * 16 + l15) * 68 + sub * 16 + quad * 4] = pkh;
        }

        const int pro = (wv * 16 + l15) * 68 + quad * 8;
        s16x8 ph0 = *(const s16x8*)&PhS[pro];
        s16x8 ph1 = *(const s16x8*)&PhS[pro + 32];
        #pragma unroll
        for (int ds = 0; ds < 4; ++ds) {
            const int ro = (ds * 16 + l15) * 72 + quad * 8;
            s16x8 vh0 = *(const s16x8*)&vhs[ro];
            s16x8 vh1 = *(const s16x8*)&vhs[ro + 32];
            racc[ds] = __builtin_amdgcn_mfma_f32_16x16x32_bf16(ph0, vh0, racc[ds], 0, 0, 0);
            racc[ds] = __builtin_amdgcn_mfma_f32_16x16x32_bf16(ph1, vh1, racc[ds], 0, 0, 0);
        }

        if (st < stHi) {
            short* kd = KhS[cur ^ 1];
            short* vd = VhS[cur ^ 1];
            *(s16x8*)&kd[srow * 72 + scol]     = pk0;
            *(s16x8*)&kd[srow * 72 + scol + 8] = pk1;
            *(s16x8*)&vd[srow * 72 + scol]     = pv0;
            *(s16x8*)&vd[srow * 72 + scol + 8] = pv1;
        }
        __syncthreads();
    }

    if (c == 0 && ntiles <= 8) {
        // fused finisher: groupnorm/gate/pack/store (identical math)
        float mean[4], rstd[4];
        #pragma unroll
        for (int r = 0; r < 4; ++r) {
            float s = racc[0][r] + racc[1][r] + racc[2][r] + racc[3][r];
            s += __shfl_xor(s, 1); s += __shfl_xor(s, 2);
            s += __shfl_xor(s, 4); s += __shfl_xor(s, 8);
            mean[r] = s * (1.0f / 64.0f);
            float vs = 0.f;
            #pragma unroll
            for (int ds = 0; ds < 4; ++ds) {
                float d = racc[ds][r] - mean[r];
                vs += d * d;
            }
            vs += __shfl_xor(vs, 1); vs += __shfl_xor(vs, 2);
            vs += __shfl_xor(vs, 4); vs += __shfl_xor(vs, 8);
            rstd[r] = rsqrtf(vs * (1.0f / 64.0f) + 1e-6f);
        }
        short* rgH = (short*)KhS + wv * 1152;
        #pragma unroll
        for (int ds = 0; ds < 4; ++ds) {
            #pragma unroll
            for (int r = 0; r < 4; ++r) {
                const int nn = n0 + wv * 16 + quad * 4 + r;
                const int d = ds * 16 + l15;
                const long gi = ((long)(b * 2048 + nn)) * 512 + h * 64 + d;
                float rg = (racc[ds][r] - mean[r]) * rstd[r] * G[gi];
                float prt = __shfl_xor(rg, 1);
                if (!(l15 & 1)) {
                    const int o = (quad * 4 + r) * 72 + ds * 16 + l15;
                    *(unsigned*)&rgH[o] = pack2(f2bf(rg), f2bf(prt));
                }
            }
        }
        #pragma unroll
        for (int p2 = 0; p2 < 2; ++p2) {
            const int row = p2 * 8 + (lane >> 3);
            const int ch = (lane & 7) * 8;
            s16x8 vh = *(const s16x8*)&rgH[row * 72 + ch];
            const int nn = n0 + wv * 16 + row;
            const long o = ((long)(b * 2048 + nn)) * 512 + h * 64 + ch;
            *(s16x8*)(RGh + o) = vh;
        }
        return;
    }

    // write partial slice [64 rows][64 cols]
    float* dst = Racc + (long)((bh * 32 + qt) * 4 + c) * 4096;
    #pragma unroll
    for (int ds = 0; ds < 4; ++ds)
        #pragma unroll
        for (int r = 0; r < 4; ++r)
            dst[(wv * 16 + quad * 4 + r) * 64 + ds * 16 + l15] = racc[ds][r];
}

// ---------------------------------------------------------------------------
// Finisher: only for multi-chunk pairs (ntiles > 8). Sums nc<=4 partials,
// then the unchanged groupnorm/gate/pack/store epilogue.
// ---------------------------------------------------------------------------
__global__ __launch_bounds__(256) void attn_finish_kernel(
    const float* __restrict__ Racc, const float* __restrict__ G,
    short* __restrict__ RGh)
{
    __shared__ __align__(16) short rgS[4608];

    const int fid = blockIdx.x;          // 0..511
    const int bh = fid & 15;
    const int qt = fid >> 4;
    const int h = bh & 7, b = bh >> 3;
    const int n0 = qt * 64;

    float l2g;
    int stLo;
    decay_params(h, n0, l2g, stLo);
    const int ntiles = qt - stLo + 1;
    if (ntiles <= 8) return;             // handled inline by chunk kernel
    const int nc = (ntiles + 7) >> 3;    // 2..4

    const int t = threadIdx.x, lane = t & 63, wv = t >> 6;
    const int quad = lane >> 4, l15 = lane & 15;

    const float* s0 = Racc + (long)((bh * 32 + qt) * 4) * 4096;
    f32x4 racc[4];
    #pragma unroll
    for (int ds = 0; ds < 4; ++ds)
        #pragma unroll
        for (int r = 0; r < 4; ++r) {
            const int o = (wv * 16 + quad * 4 + r) * 64 + ds * 16 + l15;
            float v = s0[o] + s0[4096 + o];
            if (nc > 2) v += s0[2 * 4096 + o];
            if (nc > 3) v += s0[3 * 4096 + o];
            racc[ds][r] = v;
        }

    float mean[4], rstd[4];
    #pragma unroll
    for (int r = 0; r < 4; ++r) {
        float s = racc[0][r] + racc[1][r] + racc[2][r] + racc[3][r];
        s += __shfl_xor(s, 1); s += __shfl_xor(s, 2);
        s += __shfl_xor(s, 4); s += __shfl_xor(s, 8);
        mean[r] = s * (1.0f / 64.0f);
        float vs = 0.f;
        #pragma unroll
        for (int ds = 0; ds < 4; ++ds) {
            float d = racc[ds][r] - mean[r];
            vs += d * d;
        }
        vs += __shfl_xor(vs, 1); vs += __shfl_xor(vs, 2);
        vs += __shfl_xor(vs, 4); vs += __shfl_xor(vs, 8);
        rstd[r] = rsqrtf(vs * (1.0f / 64.0f) + 1e-6f);
    }

    short* rgH = rgS + wv * 1152;
    #pragma unroll
    for (int ds = 0; ds < 4; ++ds) {
        #pragma unroll
        for (int r = 0; r < 4; ++r) {
            const int nn = n0 + wv * 16 + quad * 4 + r;
            const int d = ds * 16 + l15;
            const long gi = ((long)(b * 2048 + nn)) * 512 + h * 64 + d;
            float rg = (racc[ds][r] - mean[r]) * rstd[r] * G[gi];
            float prt = __shfl_xor(rg, 1);
            if (!(l15 & 1)) {
                const int o = (quad * 4 + r) * 72 + ds * 16 + l15;
                *(unsigned*)&rgH[o] = pack2(f2bf(rg), f2bf(prt));
            }
        }
    }
    __syncthreads();
    #pragma unroll
    for (int p2 = 0; p2 < 2; ++p2) {
        const int row = p2 * 8 + (lane >> 3);
        const int ch = (lane & 7) * 8;
        s16x8 vh = *(const s16x8*)&rgS[(wv * 1152 + row * 72 + ch)];
        const int nn = n0 + wv * 16 + row;
        const long o = ((long)(b * 2048 + nn)) * 512 + h * 64 + ch;
        *(s16x8*)(RGh + o) = vh;
    }
}

// ---------------------------------------------------------------------------
// Output projection: out = RG(bf16) @ Wo^T + bo. 32x128 tile, waves 2x2.
// Double-buffered LDS stages, ONE barrier per K-step; reg loads issued early.
// ---------------------------------------------------------------------------
__global__ __launch_bounds__(256) void projo_kernel(
    const short* __restrict__ RGh, const short* __restrict__ Woh_g,
    const float* __restrict__ bo, float* __restrict__ out)
{
    __shared__ __align__(16) char PB[46080];   // 2 stages x 23040

    const short* Wol_g = Woh_g + 262144;
    const int t = threadIdx.x, lane = t & 63, wv = t >> 6;
    const int wm = wv >> 1, wn = wv & 1;
    const int quad = lane >> 4, l15 = lane & 15;
    const int m0 = blockIdx.y * 32, n0 = blockIdx.x * 128;

    f32x4 acc[4];
    #pragma unroll
    for (int j = 0; j < 4; ++j) acc[j] = (f32x4){0.f, 0.f, 0.f, 0.f};

    const int xrow = t >> 3, xcol = (t & 7) * 4;
    const int wrow = t >> 1, wcol = (t & 1) * 16;
    const long xbase = (long)(m0 + xrow) * 512 + xcol;
    const long wbase = (long)(n0 + wrow) * 512 + wcol;

    s16x4 px;
    s16x8 pw0, pw1, pw2, pw3;
    px  = *(const s16x4*)(RGh + xbase);
    pw0 = *(const s16x8*)(Woh_g + wbase);
    pw1 = *(const s16x8*)(Woh_g + wbase + 8);
    pw2 = *(const s16x8*)(Wol_g + wbase);
    pw3 = *(const s16x8*)(Wol_g + wbase + 8);

    // prologue: write stage 0
    {
        short* XhS = (short*)PB;
        short* WhS = XhS + 1280;
        short* WlS = XhS + 6400;
        *(s16x4*)&XhS[xrow * 40 + xcol]     = px;
        *(s16x8*)&WhS[wrow * 40 + wcol]     = pw0;
        *(s16x8*)&WhS[wrow * 40 + wcol + 8] = pw1;
        *(s16x8*)&WlS[wrow * 40 + wcol]     = pw2;
        *(s16x8*)&WlS[wrow * 40 + wcol + 8] = pw3;
    }
    __syncthreads();

    for (int k0 = 0; k0 < 512; k0 += 32) {
        const int cur = (k0 >> 5) & 1;
        const bool more = (k0 + 32 < 512);
        if (more) {
            const long xo = xbase + k0 + 32;
            const long wo = wbase + k0 + 32;
            px  = *(const s16x4*)(RGh + xo);
            pw0 = *(const s16x8*)(Woh_g + wo);
            pw1 = *(const s16x8*)(Woh_g + wo + 8);
            pw2 = *(const s16x8*)(Wol_g + wo);
            pw3 = *(const s16x8*)(Wol_g + wo + 8);
        }

        const short* XhS = (const short*)(PB + cur * 23040);
        const short* WhS = XhS + 1280;
        const short* WlS = XhS + 6400;
        s16x8 ah, bh[4], bl[4];
        {
            const int ro = (wm * 16 + l15) * 40 + quad * 8;
            ah = *(const s16x8*)&XhS[ro];
        }
        #pragma unroll
        for (int s = 0; s < 4; ++s) {
            const int ro = (wn * 64 + s * 16 + l15) * 40 + quad * 8;
            bh[s] = *(const s16x8*)&WhS[ro];
            bl[s] = *(const s16x8*)&WlS[ro];
        }
        #pragma unroll
        for (int j = 0; j < 4; ++j) {
            acc[j] = __builtin_amdgcn_mfma_f32_16x16x32_bf16(ah, bh[j], acc[j], 0, 0, 0);
            acc[j] = __builtin_amdgcn_mfma_f32_16x16x32_bf16(ah, bl[j], acc[j], 0, 0, 0);
        }

        if (more) {
            short* XhD = (short*)(PB + (cur ^ 1) * 23040);
            short* WhD = XhD + 1280;
            short* WlD = XhD + 6400;
            *(s16x4*)&XhD[xrow * 40 + xcol]     = px;
            *(s16x8*)&WhD[wrow * 40 + wcol]     = pw0;
            *(s16x8*)&WhD[wrow * 40 + wcol + 8] = pw1;
            *(s16x8*)&WlD[wrow * 40 + wcol]     = pw2;
            *(s16x8*)&WlD[wrow * 40 + wcol + 8] = pw3;
        }
        __syncthreads();
    }

    float* T = (float*)PB + wv * 1152;   // 16 x 72 fp32
    #pragma unroll
    for (int ns = 0; ns < 4; ++ns) {
        const int col = n0 + wn * 64 + ns * 16 + l15;
        const float bvv = bo[col];
        #pragma unroll
        for (int r = 0; r < 4; ++r)
            T[(quad * 4 + r) * 72 + ns * 16 + l15] = acc[ns][r] + bvv;
    }
    #pragma unroll
    for (int it = 0; it < 2; ++it) {
        const int row = it * 8 + (lane >> 3);
        const int ch = (lane & 7) * 8;
        f32x4 a = *(const f32x4*)&T[row * 72 + ch];
        f32x4 c = *(const f32x4*)&T[row * 72 + ch + 4];
        const long o = (long)(m0 + wm * 16 + row) * 512 + n0 + wn * 64 + ch;
        *(f32x4*)(out + o) = a;
        *(f32x4*)(out + o + 4) = c;
    }
}

extern "C" void kernel_launch(void* const* d_in, const int* in_sizes, int n_in,
                              void* d_out, int out_size, void* d_ws, size_t ws_size,
                              hipStream_t stream) {
    const float* query = (const float*)d_in[0];
    const float* kin   = (const float*)d_in[1];
    const float* vin   = (const float*)d_in[2];
    const float* Wq = (const float*)d_in[3];
    const float* bq = (const float*)d_in[4];
    const float* Wk = (const float*)d_in[5];
    const float* bk = (const float*)d_in[6];
    const float* Wv = (const float*)d_in[7];
    const float* bv = (const float*)d_in[8];
    const float* Wg = (const float*)d_in[9];
    const float* bg = (const float*)d_in[10];
    const float* Wo = (const float*)d_in[11];
    const float* bo = (const float*)d_in[12];

    short* S = (short*)d_ws;
    const long NE = 2097152;             // 4096*512 elements
    short* WSp = S;                      // 5 MB
    short* Xsp = S + 2621440;            // (unused staging region)
    short* Qh  = Xsp + 12582912;
    short* Ql  = Qh + NE;
    short* Kh  = Ql + NE;
    short* Vth = Kh + NE;
    float* G   = (float*)(Vth + NE);     // NE floats
    short* RGh = (short*)(G + NE);
    float2* SC = (float2*)(RGh + NE);    // 2048*32 float2 = 512 KB
    float* Racc = (float*)(SC + 65536);  // 16*32*4*4096 f32 = 33.5 MB

    presplit_kernel<<<576, 256, 0, stream>>>(
        Wq, Wk, Wv, Wg, Wo, WSp, SC);
    projqkvg_kernel<<<dim3(4, 64, 4), 512, 0, stream>>>(
        query, kin, vin, WSp, bq, bk, bv, bg, SC, Qh, Ql, Kh, Vth, G);
    attn_chunk_kernel<<<2048, 256, 0, stream>>>(
        Qh, Ql, Kh, Vth, G, RGh, Racc);
    attn_finish_kernel<<<512, 256, 0, stream>>>(
        Racc, G, RGh);
    projo_kernel<<<dim3(4, 128), 256, 0, stream>>>(
        RGh, WSp + 4 * 524288, bo, (float*)d_out);
}

// Round 12
// 186.274 us; speedup vs baseline: 1.0419x; 1.0419x over previous
//
#include <hip/hip_runtime.h>
#include <math.h>

typedef float f32x4 __attribute__((ext_vector_type(4)));
typedef short s16x8 __attribute__((ext_vector_type(8)));
typedef short s16x4 __attribute__((ext_vector_type(4)));
typedef unsigned u32x4 __attribute__((ext_vector_type(4)));

__device__ __forceinline__ short f2bf(float f) {
    unsigned u = __builtin_bit_cast(unsigned, f);
    unsigned r = u + 0x7FFFu + ((u >> 16) & 1u);
    return (short)(r >> 16);
}
__device__ __forceinline__ float bf2f(short h) {
    return __builtin_bit_cast(float, ((unsigned)(unsigned short)h) << 16);
}
__device__ __forceinline__ unsigned pack2(short a, short b) {
    return (unsigned)(unsigned short)a | ((unsigned)(unsigned short)b << 16);
}
// packed f32x2 -> bf16x2, RTNE (same rounding as f2bf); low = a, high = b
__device__ __forceinline__ unsigned cvtpk(float a, float b) {
    unsigned r;
    asm("v_cvt_pk_bf16_f32 %0, %1, %2" : "=v"(r) : "v"(a), "v"(b));
    return r;
}

__device__ __forceinline__ void split16v(const float* __restrict__ p,
                                         short* __restrict__ h,
                                         short* __restrict__ l) {
    f32x4 a0 = *(const f32x4*)(p);
    f32x4 a1 = *(const f32x4*)(p + 4);
    f32x4 a2 = *(const f32x4*)(p + 8);
    f32x4 a3 = *(const f32x4*)(p + 12);
    #pragma unroll
    for (int i = 0; i < 4; ++i) {
        short t0;
        t0 = f2bf(a0[i]); h[i]      = t0; l[i]      = f2bf(a0[i] - bf2f(t0));
        t0 = f2bf(a1[i]); h[4 + i]  = t0; l[4 + i]  = f2bf(a1[i] - bf2f(t0));
        t0 = f2bf(a2[i]); h[8 + i]  = t0; l[8 + i]  = f2bf(a2[i] - bf2f(t0));
        t0 = f2bf(a3[i]); h[12 + i] = t0; l[12 + i] = f2bf(a3[i] - bf2f(t0));
    }
}

__device__ __forceinline__ void gload16(const void* g, void* l) {
    __builtin_amdgcn_global_load_lds(
        (const __attribute__((address_space(1))) unsigned int*)g,
        (__attribute__((address_space(3))) unsigned int*)l,
        16, 0, 0);
}

// decay constants for head h (shared by chunk + finish kernels)
__device__ __forceinline__ void decay_params(int h, int n0, float& l2g, int& stLo) {
    float lg0 = logf(1.0f / 32.0f), lg1 = logf(1.0f / 512.0f);
    float om = expf(lg0 + (float)h * (lg1 - lg0) * (1.0f / 7.0f));  // 1-gamma
    l2g = log2f(1.0f - om);
    int Dcut = (int)(11.5129255f / om) + 64;
    stLo = (n0 - Dcut) >> 6;
    if (stLo < 0) stLo = 0;
}

// ---------------------------------------------------------------------------
// Pre-split WEIGHTS ONLY into hi/lo bf16 + rotary cos/sin table.
// ---------------------------------------------------------------------------
__global__ __launch_bounds__(256) void presplit_kernel(
    const float* __restrict__ W0, const float* __restrict__ W1,
    const float* __restrict__ W2, const float* __restrict__ W3,
    const float* __restrict__ W4,
    short* __restrict__ Wsp, float2* __restrict__ SC)
{
    const int blk = blockIdx.x;
    const int t = threadIdx.x;
    short hbuf[16], lbuf[16];
    if (blk < 256) {
        const int w = blk >> 6, bi = blk & 63;
        const float* src = (w == 0) ? W0 : (w == 1) ? W1 : (w == 2) ? W2 : W3;
        const int idx = (bi * 256 + t) * 16;
        const int row = idx >> 9, k0 = idx & 511;
        const int ntile = row >> 7, r = row & 127;
        const int kstep = k0 >> 5, kk0 = k0 & 31;
        const int s = (r & 3) << 4;
        split16v(src + idx, hbuf, lbuf);
        short* hp = Wsp + (long)w * 524288 + (ntile * 16 + kstep) * 8192 + r * 32;
        short* lp = hp + 4096;
        const int oA = ((2 * kk0) ^ s) >> 1;
        const int oB = ((2 * kk0 + 16) ^ s) >> 1;
        *(s16x8*)(hp + oA) = *(s16x8*)(hbuf);
        *(s16x8*)(hp + oB) = *(s16x8*)(hbuf + 8);
        *(s16x8*)(lp + oA) = *(s16x8*)(lbuf);
        *(s16x8*)(lp + oB) = *(s16x8*)(lbuf + 8);
    } else if (blk < 320) {
        const int bi = blk - 256;
        const int idx = (bi * 256 + t) * 16;
        short* hi = Wsp + (long)4 * 524288;
        short* lo = hi + 262144;
        split16v(W4 + idx, hbuf, lbuf);
        *(s16x8*)(hi + idx)     = *(s16x8*)(hbuf);
        *(s16x8*)(hi + idx + 8) = *(s16x8*)(hbuf + 8);
        *(s16x8*)(lo + idx)     = *(s16x8*)(lbuf);
        *(s16x8*)(lo + idx + 8) = *(s16x8*)(lbuf + 8);
    } else {
        // rotary table: gid = pos*32 + pp
        const int gid = (blk - 320) * 256 + t;
        const int pos = gid >> 5, pp = gid & 31;
        const float theta = powf(10000.0f, -(float)pp * (1.0f / 31.0f));
        const float ang = (float)pos * theta;
        SC[gid] = make_float2(cosf(ang), sinf(ang));
    }
}

// ---------------------------------------------------------------------------
// Fused Q/K/V/G projections. 64x128 tile, 8 waves (512 thr) 2x4, BK=32.
// Triple-buffered global_load_lds staging (3 x 24 KB), counted vmcnt(3),
// raw s_barrier, XCD-locality remap, s_setprio around MFMA cluster.
// X staged as RAW fp32 (per-lane swizzled global source); hi/lo bf16 split
// in-register via v_cvt_pk_bf16_f32. Stage layout: [X fp32 8K | Wh 8K | Wl 8K].
// ---------------------------------------------------------------------------
__global__ __launch_bounds__(512, 4) void projqkvg_kernel(
    const float* __restrict__ X0, const float* __restrict__ X1,
    const float* __restrict__ X2, const short* __restrict__ Wsp,
    const float* __restrict__ bq, const float* __restrict__ bk,
    const float* __restrict__ bv, const float* __restrict__ bg,
    const float2* __restrict__ SC,
    short* __restrict__ Qh, short* __restrict__ Ql,
    short* __restrict__ Kh, short* __restrict__ Vth,
    float* __restrict__ G)
{
    __shared__ __align__(16) short SB[36864];   // 72 KB = 3 stages x 24 KB

    const int fid = blockIdx.x + 4 * (blockIdx.y + 64 * blockIdx.z);
    const int mtile = fid & 63;
    const int rr = fid >> 6;            // 0..15
    const int mode = rr & 3;
    const int ntile = rr >> 2;
    const int m0 = mtile * 64, n0 = ntile * 128;

    const int xi = (mode == 1) ? 1 : (mode == 2) ? 2 : 0;
    const float* Xf = (xi == 0) ? X0 : (xi == 1) ? X1 : X2;
    const float* bias = (mode == 0) ? bq : (mode == 1) ? bk
                       : (mode == 2) ? bv : bg;

    const int t = threadIdx.x, lane = t & 63, wv = t >> 6;   // 8 waves
    const int wm = wv >> 2, wn = wv & 3;                      // 2 x 4
    const int quad = lane >> 4, l15 = lane & 15;

    const short* Wblk = Wsp + (long)mode * 524288 + (long)ntile * 16 * 8192;

    // staging: 24 chunks of 1 KB; wave wv owns chunks wv*3 .. wv*3+2
    // chunks 0-7: X fp32 (per-lane swizzled source); 8-23: W hi/lo bf16
    const int c0 = wv * 3;
    const char* gs[3];
    int gstp[3];
    #pragma unroll
    for (int i = 0; i < 3; ++i) {
        const int c = c0 + i;
        if (c < 8) {
            const int u = c * 64 + lane;        // LDS unit = row*8 + ucol
            const int row = u >> 3, ucol = u & 7;
            gs[i] = (const char*)(Xf + (long)(m0 + row) * 512)
                    + ((ucol ^ (row & 7)) << 4);
            gstp[i] = 128;                      // 32 floats per K-step
        } else {
            gs[i] = (const char*)(Wblk + (c - 8) * 512 + lane * 8);
            gstp[i] = 16384;                    // 8192 shorts per K-step
        }
    }

    auto STAGE = [&](int stg, int ks) {
        char* dstb = (char*)SB + stg * 24576 + c0 * 1024;
        #pragma unroll
        for (int i = 0; i < 3; ++i)
            gload16(gs[i] + (long)ks * gstp[i], dstb + i * 1024);
    };

    // fragment LDS byte offsets (K-step invariant)
    int aoff[2];
    #pragma unroll
    for (int s2 = 0; s2 < 2; ++s2) {
        const int row = wm * 32 + s2 * 16 + l15;
        aoff[s2] = row * 128 + ((quad * 32) ^ ((row & 7) << 4));
    }
    const int sxw = (l15 & 3) << 4;
    int boff[2];
    #pragma unroll
    for (int s2 = 0; s2 < 2; ++s2)
        boff[s2] = 8192 + (wn * 32 + s2 * 16 + l15) * 64 + ((quad * 16) ^ sxw);

    f32x4 acc[2][2];
    #pragma unroll
    for (int i = 0; i < 2; ++i)
        #pragma unroll
        for (int j = 0; j < 2; ++j)
            acc[i][j] = (f32x4){0.f, 0.f, 0.f, 0.f};

    // prologue: fill stages 0 and 1; wait only for stage 0 (oldest 3)
    STAGE(0, 0);
    STAGE(1, 1);
    asm volatile("s_waitcnt vmcnt(3)" ::: "memory");
    __builtin_amdgcn_s_barrier();

    int cur = 0;
    for (int ks = 0; ks < 16; ++ks) {
        if (ks < 14) {
            int fill = cur + 2; if (fill >= 3) fill -= 3;
            STAGE(fill, ks + 2);
        }
        __builtin_amdgcn_sched_barrier(0);

        const char* stg = (const char*)SB + cur * 24576;
        s16x8 ah[2], al[2], bh[2], bl[2];
        #pragma unroll
        for (int s2 = 0; s2 < 2; ++s2) {
            f32x4 x0 = *(const f32x4*)(stg + aoff[s2]);
            f32x4 x1 = *(const f32x4*)(stg + (aoff[s2] ^ 16));
            u32x4 hv, lv;
            #pragma unroll
            for (int j = 0; j < 2; ++j) {
                float a0 = x0[2 * j], b0 = x0[2 * j + 1];
                float a1 = x1[2 * j], b1 = x1[2 * j + 1];
                unsigned h0 = cvtpk(a0, b0);
                unsigned h1 = cvtpk(a1, b1);
                hv[j]     = h0;
                hv[2 + j] = h1;
                float fa0 = __builtin_bit_cast(float, h0 << 16);
                float fb0 = __builtin_bit_cast(float, h0 & 0xFFFF0000u);
                float fa1 = __builtin_bit_cast(float, h1 << 16);
                float fb1 = __builtin_bit_cast(float, h1 & 0xFFFF0000u);
                lv[j]     = cvtpk(a0 - fa0, b0 - fb0);
                lv[2 + j] = cvtpk(a1 - fa1, b1 - fb1);
            }
            ah[s2] = __builtin_bit_cast(s16x8, hv);
            al[s2] = __builtin_bit_cast(s16x8, lv);
        }
        #pragma unroll
        for (int s2 = 0; s2 < 2; ++s2) {
            bh[s2] = *(const s16x8*)(stg + boff[s2]);
            bl[s2] = *(const s16x8*)(stg + 8192 + boff[s2]);
        }
        __builtin_amdgcn_s_setprio(1);
        #pragma unroll
        for (int i = 0; i < 2; ++i)
            #pragma unroll
            for (int j = 0; j < 2; ++j) {
                acc[i][j] = __builtin_amdgcn_mfma_f32_16x16x32_bf16(ah[i], bh[j], acc[i][j], 0, 0, 0);
                acc[i][j] = __builtin_amdgcn_mfma_f32_16x16x32_bf16(al[i], bh[j], acc[i][j], 0, 0, 0);
                acc[i][j] = __builtin_amdgcn_mfma_f32_16x16x32_bf16(ah[i], bl[j], acc[i][j], 0, 0, 0);
            }
        __builtin_amdgcn_s_setprio(0);

        if (ks < 14)       asm volatile("s_waitcnt vmcnt(3)" ::: "memory");
        else if (ks == 14) asm volatile("s_waitcnt vmcnt(0)" ::: "memory");
        __builtin_amdgcn_sched_barrier(0);
        __builtin_amdgcn_s_barrier();

        cur += 1; if (cur >= 3) cur -= 3;
    }

    __syncthreads();   // full drain; LDS reusable by epilogues

    const int bb = m0 >> 11, posb = m0 & 2047;

    if (mode == 0) {
        short* Thi = SB + wv * 1280;            // 16 x 40
        short* Tlo = Thi + 640;
        const int head = (n0 >> 6) + (wn >> 1);
        const int dbase = (wn & 1) * 32;
        #pragma unroll
        for (int ms = 0; ms < 2; ++ms) {
            #pragma unroll
            for (int ns = 0; ns < 2; ++ns) {
                const int col = n0 + wn * 32 + ns * 16 + l15;
                const float bvv = bias[col];
                const int pp = (col & 63) >> 1;
                #pragma unroll
                for (int r = 0; r < 4; ++r) {
                    const int m = m0 + wm * 32 + ms * 16 + quad * 4 + r;
                    const int pos = m & 2047;
                    float x = acc[ms][ns][r] + bvv;
                    float prt = __shfl_xor(x, 1);
                    float2 sc = SC[pos * 32 + pp];
                    float y0 = x * sc.x - prt * sc.y;
                    float y1 = prt * sc.x + x * sc.y;
                    if (!(l15 & 1)) {
                        short h0 = f2bf(y0), h1 = f2bf(y1);
                        short l0 = f2bf(y0 - bf2f(h0)), l1 = f2bf(y1 - bf2f(h1));
                        const int o = (quad * 4 + r) * 40 + ns * 16 + l15;
                        *(unsigned*)&Thi[o] = pack2(h0, h1);
                        *(unsigned*)&Tlo[o] = pack2(l0, l1);
                    }
                }
            }
            const int mrow = wm * 32 + ms * 16;
            const int row = lane >> 2, ch = (lane & 3) * 8;
            s16x8 vh = *(const s16x8*)&Thi[row * 40 + ch];
            s16x8 vl = *(const s16x8*)&Tlo[row * 40 + ch];
            const long o = ((long)(bb * 8 + head) * 2048 + posb + mrow + row) * 64 + dbase + ch;
            *(s16x8*)(Qh + o) = vh;
            *(s16x8*)(Ql + o) = vl;
        }
    } else if (mode == 1) {
        short* Thi = SB + wv * 640;             // 16 x 40
        const int head = (n0 >> 6) + (wn >> 1);
        const int dbase = (wn & 1) * 32;
        #pragma unroll
        for (int ms = 0; ms < 2; ++ms) {
            #pragma unroll
            for (int ns = 0; ns < 2; ++ns) {
                const int col = n0 + wn * 32 + ns * 16 + l15;
                const float bvv = bias[col];
                const int pp = (col & 63) >> 1;
                #pragma unroll
                for (int r = 0; r < 4; ++r) {
                    const int m = m0 + wm * 32 + ms * 16 + quad * 4 + r;
                    const int pos = m & 2047;
                    float x = acc[ms][ns][r] + bvv;
                    float prt = __shfl_xor(x, 1);
                    float2 sc = SC[pos * 32 + pp];
                    float y0 = (x * sc.x - prt * sc.y) * 0.125f;
                    float y1 = (prt * sc.x + x * sc.y) * 0.125f;
                    if (!(l15 & 1)) {
                        const int o = (quad * 4 + r) * 40 + ns * 16 + l15;
                        *(unsigned*)&Thi[o] = pack2(f2bf(y0), f2bf(y1));
                    }
                }
            }
            const int mrow = wm * 32 + ms * 16;
            const int row = lane >> 2, ch = (lane & 3) * 8;
            s16x8 vh = *(const s16x8*)&Thi[row * 40 + ch];
            const long o = ((long)(bb * 8 + head) * 2048 + posb + mrow + row) * 64 + dbase + ch;
            *(s16x8*)(Kh + o) = vh;
        }
    } else if (mode == 2) {
        short* T2 = SB;   // 128 x 72
        #pragma unroll
        for (int ns = 0; ns < 2; ++ns) {
            const int col = n0 + wn * 32 + ns * 16 + l15;
            const float bvv = bias[col];
            #pragma unroll
            for (int ms = 0; ms < 2; ++ms) {
                s16x4 pk;
                #pragma unroll
                for (int r = 0; r < 4; ++r)
                    pk[r] = f2bf(acc[ms][ns][r] + bvv);
                *(s16x4*)&T2[(wn * 32 + ns * 16 + l15) * 72
                             + wm * 32 + ms * 16 + quad * 4] = pk;
            }
        }
        __syncthreads();
        #pragma unroll
        for (int pass = 0; pass < 2; ++pass) {
            const int row = pass * 64 + (t >> 3);    // 0..127
            const int ch = (t & 7) * 8;
            s16x8 v = *(const s16x8*)&T2[row * 72 + ch];
            const int head = (n0 >> 6) + (row >> 6);
            const int d = row & 63;
            const long o = ((long)(bb * 8 + head) * 64 + d) * 2048 + posb + ch;
            *(s16x8*)(Vth + o) = v;
        }
    } else {
        #pragma unroll
        for (int ns = 0; ns < 2; ++ns) {
            const int col = n0 + wn * 32 + ns * 16 + l15;
            const float bvv = bias[col];
            #pragma unroll
            for (int ms = 0; ms < 2; ++ms)
                #pragma unroll
                for (int r = 0; r < 4; ++r) {
                    const int m = m0 + wm * 32 + ms * 16 + quad * 4 + r;
                    float x = acc[ms][ns][r] + bvv;
                    G[(long)m * 512 + col] = x / (1.0f + expf(-x));
                }
        }
    }
}

// ---------------------------------------------------------------------------
// Retention attention, split-K (CHUNK=16), double-buffered K/V LDS, ONE
// barrier/tile, s_setprio around MFMA clusters (independent blocks at
// different phases -> scheduler arbitration pays). Single-chunk pairs
// (c==0 && ntiles<=16) run the epilogue inline; else partials to Racc.
// ---------------------------------------------------------------------------
__global__ __launch_bounds__(256) void attn_chunk_kernel(
    const short* __restrict__ Qh_g, const short* __restrict__ Ql_g,
    const short* __restrict__ Kh_g, const short* __restrict__ Vth_g,
    const float* __restrict__ G, short* __restrict__ RGh,
    float* __restrict__ Racc)
{
    __shared__ __align__(16) short KhS[2][4608], VhS[2][4608];
    __shared__ __align__(16) short PhS[4352];

    const int fid = blockIdx.x;          // 0..1023
    const int bh = fid & 15;
    const int rest = fid >> 4;
    const int qt = rest & 31;
    const int c  = rest >> 5;            // 0..1
    const int h = bh & 7, b = bh >> 3;
    const int n0 = qt * 64;

    float l2g;
    int stLo;
    decay_params(h, n0, l2g, stLo);
    const int ntiles = qt - stLo + 1;
    const int st0 = stLo + c * 16;
    if (st0 > qt) return;
    const int stHi = min(st0 + 15, qt);

    const int t = threadIdx.x, lane = t & 63, wv = t >> 6;
    const int quad = lane >> 4, l15 = lane & 15;
    const long base = (long)bh * 2048 * 64;

    float gneg[16];
    #pragma unroll
    for (int i = 0; i < 16; ++i)
        gneg[i] = exp2f(-(float)((i >> 2) * 16 + (i & 3)) * l2g);

    const int srow = t >> 2;
    const int scol = (t & 3) * 16;
    const int n = n0 + wv * 16 + l15;

    s16x8 qh[2], ql[2];
    {
        const short* qp  = Qh_g + base + (long)(n0 + wv * 16 + l15) * 64 + quad * 8;
        const short* qp2 = Ql_g + base + (long)(n0 + wv * 16 + l15) * 64 + quad * 8;
        qh[0] = *(const s16x8*)qp;
        qh[1] = *(const s16x8*)(qp + 32);
        ql[0] = *(const s16x8*)qp2;
        ql[1] = *(const s16x8*)(qp2 + 32);
    }

    f32x4 racc[4];
    #pragma unroll
    for (int i = 0; i < 4; ++i) racc[i] = (f32x4){0.f, 0.f, 0.f, 0.f};

    // prologue: load tile st0 and write buffer 0
    s16x8 pk0, pk1, pv0, pv1;
    {
        const long ko = base + (long)(st0 * 64 + srow) * 64 + scol;
        pk0 = *(const s16x8*)(Kh_g + ko);
        pk1 = *(const s16x8*)(Kh_g + ko + 8);
        const long vo = base + (long)srow * 2048 + st0 * 64 + scol;
        pv0 = *(const s16x8*)(Vth_g + vo);
        pv1 = *(const s16x8*)(Vth_g + vo + 8);
    }
    *(s16x8*)&KhS[0][srow * 72 + scol]     = pk0;
    *(s16x8*)&KhS[0][srow * 72 + scol + 8] = pk1;
    *(s16x8*)&VhS[0][srow * 72 + scol]     = pv0;
    *(s16x8*)&VhS[0][srow * 72 + scol + 8] = pv1;
    __syncthreads();

    int cur = 0;
    for (int st = st0; st <= stHi; ++st, cur ^= 1) {
        if (st < stHi) {
            const long ko = base + (long)((st + 1) * 64 + srow) * 64 + scol;
            pk0 = *(const s16x8*)(Kh_g + ko);
            pk1 = *(const s16x8*)(Kh_g + ko + 8);
            const long vo = base + (long)srow * 2048 + (st + 1) * 64 + scol;
            pv0 = *(const s16x8*)(Vth_g + vo);
            pv1 = *(const s16x8*)(Vth_g + vo + 8);
        }

        const short* khs = KhS[cur];
        const short* vhs = VhS[cur];
        const int s0 = st * 64;
        const float t0 = exp2f((float)(n - s0 - quad * 4) * l2g);

        #pragma unroll
        for (int sub = 0; sub < 4; ++sub) {
            const int ro = (sub * 16 + l15) * 72 + quad * 8;
            s16x8 kh0 = *(const s16x8*)&khs[ro];
            s16x8 kh1 = *(const s16x8*)&khs[ro + 32];
            f32x4 sacc = (f32x4){0.f, 0.f, 0.f, 0.f};
            __builtin_amdgcn_s_setprio(1);
            sacc = __builtin_amdgcn_mfma_f32_16x16x32_bf16(kh0, qh[0], sacc, 0, 0, 0);
            sacc = __builtin_amdgcn_mfma_f32_16x16x32_bf16(kh1, qh[1], sacc, 0, 0, 0);
            sacc = __builtin_amdgcn_mfma_f32_16x16x32_bf16(kh0, ql[0], sacc, 0, 0, 0);
            sacc = __builtin_amdgcn_mfma_f32_16x16x32_bf16(kh1, ql[1], sacc, 0, 0, 0);
            __builtin_amdgcn_s_setprio(0);

            const int sb = s0 + sub * 16 + quad * 4;
            s16x4 pkh;
            #pragma unroll
            for (int r = 0; r < 4; ++r) {
                const int s = sb + r;
                const float wgt = (n >= s) ? t0 * gneg[sub * 4 + r] : 0.0f;
                pkh[r] = f2bf(sacc[r] * wgt);
            }
            *(s16x4*)&PhS[(wv * 16 + l15) * 68 + sub * 16 + quad * 4] = pkh;
        }

        const int pro = (wv * 16 + l15) * 68 + quad * 8;
        s16x8 ph0 = *(const s16x8*)&PhS[pro];
        s16x8 ph1 = *(const s16x8*)&PhS[pro + 32];
        __builtin_amdgcn_s_setprio(1);
        #pragma unroll
        for (int ds = 0; ds < 4; ++ds) {
            const int ro = (ds * 16 + l15) * 72 + quad * 8;
            s16x8 vh0 = *(const s16x8*)&vhs[ro];
            s16x8 vh1 = *(const s16x8*)&vhs[ro + 32];
            racc[ds] = __builtin_amdgcn_mfma_f32_16x16x32_bf16(ph0, vh0, racc[ds], 0, 0, 0);
            racc[ds] = __builtin_amdgcn_mfma_f32_16x16x32_bf16(ph1, vh1, racc[ds], 0, 0, 0);
        }
        __builtin_amdgcn_s_setprio(0);

        if (st < stHi) {
            short* kd = KhS[cur ^ 1];
            short* vd = VhS[cur ^ 1];
            *(s16x8*)&kd[srow * 72 + scol]     = pk0;
            *(s16x8*)&kd[srow * 72 + scol + 8] = pk1;
            *(s16x8*)&vd[srow * 72 + scol]     = pv0;
            *(s16x8*)&vd[srow * 72 + scol + 8] = pv1;
        }
        __syncthreads();
    }

    if (c == 0 && ntiles <= 16) {
        // fused finisher: groupnorm/gate/pack/store (identical math)
        float mean[4], rstd[4];
        #pragma unroll
        for (int r = 0; r < 4; ++r) {
            float s = racc[0][r] + racc[1][r] + racc[2][r] + racc[3][r];
            s += __shfl_xor(s, 1); s += __shfl_xor(s, 2);
            s += __shfl_xor(s, 4); s += __shfl_xor(s, 8);
            mean[r] = s * (1.0f / 64.0f);
            float vs = 0.f;
            #pragma unroll
            for (int ds = 0; ds < 4; ++ds) {
                float d = racc[ds][r] - mean[r];
                vs += d * d;
            }
            vs += __shfl_xor(vs, 1); vs += __shfl_xor(vs, 2);
            vs += __shfl_xor(vs, 4); vs += __shfl_xor(vs, 8);
            rstd[r] = rsqrtf(vs * (1.0f / 64.0f) + 1e-6f);
        }
        short* rgH = (short*)KhS + wv * 1152;
        #pragma unroll
        for (int ds = 0; ds < 4; ++ds) {
            #pragma unroll
            for (int r = 0; r < 4; ++r) {
                const int nn = n0 + wv * 16 + quad * 4 + r;
                const int d = ds * 16 + l15;
                const long gi = ((long)(b * 2048 + nn)) * 512 + h * 64 + d;
                float rg = (racc[ds][r] - mean[r]) * rstd[r] * G[gi];
                float prt = __shfl_xor(rg, 1);
                if (!(l15 & 1)) {
                    const int o = (quad * 4 + r) * 72 + ds * 16 + l15;
                    *(unsigned*)&rgH[o] = pack2(f2bf(rg), f2bf(prt));
                }
            }
        }
        #pragma unroll
        for (int p2 = 0; p2 < 2; ++p2) {
            const int row = p2 * 8 + (lane >> 3);
            const int ch = (lane & 7) * 8;
            s16x8 vh = *(const s16x8*)&rgH[row * 72 + ch];
            const int nn = n0 + wv * 16 + row;
            const long o = ((long)(b * 2048 + nn)) * 512 + h * 64 + ch;
            *(s16x8*)(RGh + o) = vh;
        }
        return;
    }

    // write partial slice [64 rows][64 cols]
    float* dst = Racc + (long)((bh * 32 + qt) * 2 + c) * 4096;
    #pragma unroll
    for (int ds = 0; ds < 4; ++ds)
        #pragma unroll
        for (int r = 0; r < 4; ++r)
            dst[(wv * 16 + quad * 4 + r) * 64 + ds * 16 + l15] = racc[ds][r];
}

// ---------------------------------------------------------------------------
// Finisher: only for two-chunk pairs (ntiles > 16). Sums 2 partials, then
// the unchanged groupnorm/gate/pack/store epilogue.
// ---------------------------------------------------------------------------
__global__ __launch_bounds__(256) void attn_finish_kernel(
    const float* __restrict__ Racc, const float* __restrict__ G,
    short* __restrict__ RGh)
{
    __shared__ __align__(16) short rgS[4608];

    const int fid = blockIdx.x;          // 0..511
    const int bh = fid & 15;
    const int qt = fid >> 4;
    const int h = bh & 7, b = bh >> 3;
    const int n0 = qt * 64;

    float l2g;
    int stLo;
    decay_params(h, n0, l2g, stLo);
    const int ntiles = qt - stLo + 1;
    if (ntiles <= 16) return;            // handled inline by chunk kernel

    const int t = threadIdx.x, lane = t & 63, wv = t >> 6;
    const int quad = lane >> 4, l15 = lane & 15;

    const float* s0 = Racc + (long)((bh * 32 + qt) * 2) * 4096;
    f32x4 racc[4];
    #pragma unroll
    for (int ds = 0; ds < 4; ++ds)
        #pragma unroll
        for (int r = 0; r < 4; ++r) {
            const int o = (wv * 16 + quad * 4 + r) * 64 + ds * 16 + l15;
            racc[ds][r] = s0[o] + s0[4096 + o];
        }

    float mean[4], rstd[4];
    #pragma unroll
    for (int r = 0; r < 4; ++r) {
        float s = racc[0][r] + racc[1][r] + racc[2][r] + racc[3][r];
        s += __shfl_xor(s, 1); s += __shfl_xor(s, 2);
        s += __shfl_xor(s, 4); s += __shfl_xor(s, 8);
        mean[r] = s * (1.0f / 64.0f);
        float vs = 0.f;
        #pragma unroll
        for (int ds = 0; ds < 4; ++ds) {
            float d = racc[ds][r] - mean[r];
            vs += d * d;
        }
        vs += __shfl_xor(vs, 1); vs += __shfl_xor(vs, 2);
        vs += __shfl_xor(vs, 4); vs += __shfl_xor(vs, 8);
        rstd[r] = rsqrtf(vs * (1.0f / 64.0f) + 1e-6f);
    }

    short* rgH = rgS + wv * 1152;
    #pragma unroll
    for (int ds = 0; ds < 4; ++ds) {
        #pragma unroll
        for (int r = 0; r < 4; ++r) {
            const int nn = n0 + wv * 16 + quad * 4 + r;
            const int d = ds * 16 + l15;
            const long gi = ((long)(b * 2048 + nn)) * 512 + h * 64 + d;
            float rg = (racc[ds][r] - mean[r]) * rstd[r] * G[gi];
            float prt = __shfl_xor(rg, 1);
            if (!(l15 & 1)) {
                const int o = (quad * 4 + r) * 72 + ds * 16 + l15;
                *(unsigned*)&rgH[o] = pack2(f2bf(rg), f2bf(prt));
            }
        }
    }
    __syncthreads();
    #pragma unroll
    for (int p2 = 0; p2 < 2; ++p2) {
        const int row = p2 * 8 + (lane >> 3);
        const int ch = (lane & 7) * 8;
        s16x8 vh = *(const s16x8*)&rgS[(wv * 1152 + row * 72 + ch)];
        const int nn = n0 + wv * 16 + row;
        const long o = ((long)(b * 2048 + nn)) * 512 + h * 64 + ch;
        *(s16x8*)(RGh + o) = vh;
    }
}

// ---------------------------------------------------------------------------
// Output projection: out = RG(bf16) @ Wo^T + bo. 32x128 tile, waves 2x2.
// Double-buffered LDS stages, ONE barrier per K-step; reg loads issued early.
// ---------------------------------------------------------------------------
__global__ __launch_bounds__(256) void projo_kernel(
    const short* __restrict__ RGh, const short* __restrict__ Woh_g,
    const float* __restrict__ bo, float* __restrict__ out)
{
    __shared__ __align__(16) char PB[46080];   // 2 stages x 23040

    const short* Wol_g = Woh_g + 262144;
    const int t = threadIdx.x, lane = t & 63, wv = t >> 6;
    const int wm = wv >> 1, wn = wv & 1;
    const int quad = lane >> 4, l15 = lane & 15;
    const int m0 = blockIdx.y * 32, n0 = blockIdx.x * 128;

    f32x4 acc[4];
    #pragma unroll
    for (int j = 0; j < 4; ++j) acc[j] = (f32x4){0.f, 0.f, 0.f, 0.f};

    const int xrow = t >> 3, xcol = (t & 7) * 4;
    const int wrow = t >> 1, wcol = (t & 1) * 16;
    const long xbase = (long)(m0 + xrow) * 512 + xcol;
    const long wbase = (long)(n0 + wrow) * 512 + wcol;

    s16x4 px;
    s16x8 pw0, pw1, pw2, pw3;
    px  = *(const s16x4*)(RGh + xbase);
    pw0 = *(const s16x8*)(Woh_g + wbase);
    pw1 = *(const s16x8*)(Woh_g + wbase + 8);
    pw2 = *(const s16x8*)(Wol_g + wbase);
    pw3 = *(const s16x8*)(Wol_g + wbase + 8);

    // prologue: write stage 0
    {
        short* XhS = (short*)PB;
        short* WhS = XhS + 1280;
        short* WlS = XhS + 6400;
        *(s16x4*)&XhS[xrow * 40 + xcol]     = px;
        *(s16x8*)&WhS[wrow * 40 + wcol]     = pw0;
        *(s16x8*)&WhS[wrow * 40 + wcol + 8] = pw1;
        *(s16x8*)&WlS[wrow * 40 + wcol]     = pw2;
        *(s16x8*)&WlS[wrow * 40 + wcol + 8] = pw3;
    }
    __syncthreads();

    for (int k0 = 0; k0 < 512; k0 += 32) {
        const int cur = (k0 >> 5) & 1;
        const bool more = (k0 + 32 < 512);
        if (more) {
            const long xo = xbase + k0 + 32;
            const long wo = wbase + k0 + 32;
            px  = *(const s16x4*)(RGh + xo);
            pw0 = *(const s16x8*)(Woh_g + wo);
            pw1 = *(const s16x8*)(Woh_g + wo + 8);
            pw2 = *(const s16x8*)(Wol_g + wo);
            pw3 = *(const s16x8*)(Wol_g + wo + 8);
        }

        const short* XhS = (const short*)(PB + cur * 23040);
        const short* WhS = XhS + 1280;
        const short* WlS = XhS + 6400;
        s16x8 ah, bh[4], bl[4];
        {
            const int ro = (wm * 16 + l15) * 40 + quad * 8;
            ah = *(const s16x8*)&XhS[ro];
        }
        #pragma unroll
        for (int s = 0; s < 4; ++s) {
            const int ro = (wn * 64 + s * 16 + l15) * 40 + quad * 8;
            bh[s] = *(const s16x8*)&WhS[ro];
            bl[s] = *(const s16x8*)&WlS[ro];
        }
        #pragma unroll
        for (int j = 0; j < 4; ++j) {
            acc[j] = __builtin_amdgcn_mfma_f32_16x16x32_bf16(ah, bh[j], acc[j], 0, 0, 0);
            acc[j] = __builtin_amdgcn_mfma_f32_16x16x32_bf16(ah, bl[j], acc[j], 0, 0, 0);
        }

        if (more) {
            short* XhD = (short*)(PB + (cur ^ 1) * 23040);
            short* WhD = XhD + 1280;
            short* WlD = XhD + 6400;
            *(s16x4*)&XhD[xrow * 40 + xcol]     = px;
            *(s16x8*)&WhD[wrow * 40 + wcol]     = pw0;
            *(s16x8*)&WhD[wrow * 40 + wcol + 8] = pw1;
            *(s16x8*)&WlD[wrow * 40 + wcol]     = pw2;
            *(s16x8*)&WlD[wrow * 40 + wcol + 8] = pw3;
        }
        __syncthreads();
    }

    float* T = (float*)PB + wv * 1152;   // 16 x 72 fp32
    #pragma unroll
    for (int ns = 0; ns < 4; ++ns) {
        const int col = n0 + wn * 64 + ns * 16 + l15;
        const float bvv = bo[col];
        #pragma unroll
        for (int r = 0; r < 4; ++r)
            T[(quad * 4 + r) * 72 + ns * 16 + l15] = acc[ns][r] + bvv;
    }
    #pragma unroll
    for (int it = 0; it < 2; ++it) {
        const int row = it * 8 + (lane >> 3);
        const int ch = (lane & 7) * 8;
        f32x4 a = *(const f32x4*)&T[row * 72 + ch];
        f32x4 c = *(const f32x4*)&T[row * 72 + ch + 4];
        const long o = (long)(m0 + wm * 16 + row) * 512 + n0 + wn * 64 + ch;
        *(f32x4*)(out + o) = a;
        *(f32x4*)(out + o + 4) = c;
    }
}

extern "C" void kernel_launch(void* const* d_in, const int* in_sizes, int n_in,
                              void* d_out, int out_size, void* d_ws, size_t ws_size,
                              hipStream_t stream) {
    const float* query = (const float*)d_in[0];
    const float* kin   = (const float*)d_in[1];
    const float* vin   = (const float*)d_in[2];
    const float* Wq = (const float*)d_in[3];
    const float* bq = (const float*)d_in[4];
    const float* Wk = (const float*)d_in[5];
    const float* bk = (const float*)d_in[6];
    const float* Wv = (const float*)d_in[7];
    const float* bv = (const float*)d_in[8];
    const float* Wg = (const float*)d_in[9];
    const float* bg = (const float*)d_in[10];
    const float* Wo = (const float*)d_in[11];
    const float* bo = (const float*)d_in[12];

    short* S = (short*)d_ws;
    const long NE = 2097152;             // 4096*512 elements
    short* WSp = S;                      // 5 MB
    short* Xsp = S + 2621440;            // scratch region (Racc)
    short* Qh  = Xsp + 12582912;
    short* Ql  = Qh + NE;
    short* Kh  = Ql + NE;
    short* Vth = Kh + NE;
    float* G   = (float*)(Vth + NE);     // NE floats
    short* RGh = (short*)(G + NE);
    float2* SC = (float2*)(RGh + NE);    // 2048*32 float2 = 512 KB
    float* Racc = (float*)Xsp;           // 16*32*2*4096 f32 = 16 MB

    presplit_kernel<<<576, 256, 0, stream>>>(
        Wq, Wk, Wv, Wg, Wo, WSp, SC);
    projqkvg_kernel<<<dim3(4, 64, 4), 512, 0, stream>>>(
        query, kin, vin, WSp, bq, bk, bv, bg, SC, Qh, Ql, Kh, Vth, G);
    attn_chunk_kernel<<<1024, 256, 0, stream>>>(
        Qh, Ql, Kh, Vth, G, RGh, Racc);
    attn_finish_kernel<<<512, 256, 0, stream>>>(
        Racc, G, RGh);
    projo_kernel<<<dim3(4, 128), 256, 0, stream>>>(
        RGh, WSp + 4 * 524288, bo, (float*)d_out);
}

// Round 13
// 181.460 us; speedup vs baseline: 1.0696x; 1.0265x over previous
//
#include <hip/hip_runtime.h>
#include <math.h>

typedef float f32x4 __attribute__((ext_vector_type(4)));
typedef short s16x8 __attribute__((ext_vector_type(8)));
typedef short s16x4 __attribute__((ext_vector_type(4)));
typedef unsigned u32x4 __attribute__((ext_vector_type(4)));

__device__ __forceinline__ short f2bf(float f) {
    unsigned u = __builtin_bit_cast(unsigned, f);
    unsigned r = u + 0x7FFFu + ((u >> 16) & 1u);
    return (short)(r >> 16);
}
__device__ __forceinline__ float bf2f(short h) {
    return __builtin_bit_cast(float, ((unsigned)(unsigned short)h) << 16);
}
__device__ __forceinline__ unsigned pack2(short a, short b) {
    return (unsigned)(unsigned short)a | ((unsigned)(unsigned short)b << 16);
}
// packed f32x2 -> bf16x2, RTNE (same rounding as f2bf); low = a, high = b
__device__ __forceinline__ unsigned cvtpk(float a, float b) {
    unsigned r;
    asm("v_cvt_pk_bf16_f32 %0, %1, %2" : "=v"(r) : "v"(a), "v"(b));
    return r;
}

__device__ __forceinline__ void split16v(const float* __restrict__ p,
                                         short* __restrict__ h,
                                         short* __restrict__ l) {
    f32x4 a0 = *(const f32x4*)(p);
    f32x4 a1 = *(const f32x4*)(p + 4);
    f32x4 a2 = *(const f32x4*)(p + 8);
    f32x4 a3 = *(const f32x4*)(p + 12);
    #pragma unroll
    for (int i = 0; i < 4; ++i) {
        short t0;
        t0 = f2bf(a0[i]); h[i]      = t0; l[i]      = f2bf(a0[i] - bf2f(t0));
        t0 = f2bf(a1[i]); h[4 + i]  = t0; l[4 + i]  = f2bf(a1[i] - bf2f(t0));
        t0 = f2bf(a2[i]); h[8 + i]  = t0; l[8 + i]  = f2bf(a2[i] - bf2f(t0));
        t0 = f2bf(a3[i]); h[12 + i] = t0; l[12 + i] = f2bf(a3[i] - bf2f(t0));
    }
}

__device__ __forceinline__ void gload16(const void* g, void* l) {
    __builtin_amdgcn_global_load_lds(
        (const __attribute__((address_space(1))) unsigned int*)g,
        (__attribute__((address_space(3))) unsigned int*)l,
        16, 0, 0);
}

// decay constants for head h (shared by chunk + finish kernels)
__device__ __forceinline__ void decay_params(int h, int n0, float& l2g, int& stLo) {
    float lg0 = logf(1.0f / 32.0f), lg1 = logf(1.0f / 512.0f);
    float om = expf(lg0 + (float)h * (lg1 - lg0) * (1.0f / 7.0f));  // 1-gamma
    l2g = log2f(1.0f - om);
    int Dcut = (int)(11.5129255f / om) + 64;
    stLo = (n0 - Dcut) >> 6;
    if (stLo < 0) stLo = 0;
}

// ---------------------------------------------------------------------------
// Pre-split WEIGHTS ONLY into hi/lo bf16 + rotary cos/sin table.
// ---------------------------------------------------------------------------
__global__ __launch_bounds__(256) void presplit_kernel(
    const float* __restrict__ W0, const float* __restrict__ W1,
    const float* __restrict__ W2, const float* __restrict__ W3,
    const float* __restrict__ W4,
    short* __restrict__ Wsp, float2* __restrict__ SC)
{
    const int blk = blockIdx.x;
    const int t = threadIdx.x;
    short hbuf[16], lbuf[16];
    if (blk < 256) {
        const int w = blk >> 6, bi = blk & 63;
        const float* src = (w == 0) ? W0 : (w == 1) ? W1 : (w == 2) ? W2 : W3;
        const int idx = (bi * 256 + t) * 16;
        const int row = idx >> 9, k0 = idx & 511;
        const int ntile = row >> 7, r = row & 127;
        const int kstep = k0 >> 5, kk0 = k0 & 31;
        const int s = (r & 3) << 4;
        split16v(src + idx, hbuf, lbuf);
        short* hp = Wsp + (long)w * 524288 + (ntile * 16 + kstep) * 8192 + r * 32;
        short* lp = hp + 4096;
        const int oA = ((2 * kk0) ^ s) >> 1;
        const int oB = ((2 * kk0 + 16) ^ s) >> 1;
        *(s16x8*)(hp + oA) = *(s16x8*)(hbuf);
        *(s16x8*)(hp + oB) = *(s16x8*)(hbuf + 8);
        *(s16x8*)(lp + oA) = *(s16x8*)(lbuf);
        *(s16x8*)(lp + oB) = *(s16x8*)(lbuf + 8);
    } else if (blk < 320) {
        const int bi = blk - 256;
        const int idx = (bi * 256 + t) * 16;
        short* hi = Wsp + (long)4 * 524288;
        short* lo = hi + 262144;
        split16v(W4 + idx, hbuf, lbuf);
        *(s16x8*)(hi + idx)     = *(s16x8*)(hbuf);
        *(s16x8*)(hi + idx + 8) = *(s16x8*)(hbuf + 8);
        *(s16x8*)(lo + idx)     = *(s16x8*)(lbuf);
        *(s16x8*)(lo + idx + 8) = *(s16x8*)(lbuf + 8);
    } else {
        // rotary table: gid = pos*32 + pp
        const int gid = (blk - 320) * 256 + t;
        const int pos = gid >> 5, pp = gid & 31;
        const float theta = powf(10000.0f, -(float)pp * (1.0f / 31.0f));
        const float ang = (float)pos * theta;
        SC[gid] = make_float2(cosf(ang), sinf(ang));
    }
}

// ---------------------------------------------------------------------------
// Fused Q/K/V/G projections. 64x128 tile, 8 waves (512 thr) as 4x2
// (wm=wv>>1 rows, wn=wv&1 col-halves): each wave owns a 16x64 output slab
// (one full head) -> X hi/lo split redundancy drops 4x -> 2x (split VALU
// halves). Per-output accumulation order unchanged (bitwise identical).
// Triple-buffered global_load_lds staging (3 x 24 KB), counted vmcnt(3),
// raw s_barrier, XCD-locality remap, s_setprio around MFMA cluster.
// ---------------------------------------------------------------------------
__global__ __launch_bounds__(512, 4) void projqkvg_kernel(
    const float* __restrict__ X0, const float* __restrict__ X1,
    const float* __restrict__ X2, const short* __restrict__ Wsp,
    const float* __restrict__ bq, const float* __restrict__ bk,
    const float* __restrict__ bv, const float* __restrict__ bg,
    const float2* __restrict__ SC,
    short* __restrict__ Qh, short* __restrict__ Ql,
    short* __restrict__ Kh, short* __restrict__ Vth,
    float* __restrict__ G)
{
    __shared__ __align__(16) short SB[36864];   // 72 KB = 3 stages x 24 KB

    const int fid = blockIdx.x + 4 * (blockIdx.y + 64 * blockIdx.z);
    const int mtile = fid & 63;
    const int rr = fid >> 6;            // 0..15
    const int mode = rr & 3;
    const int ntile = rr >> 2;
    const int m0 = mtile * 64, n0 = ntile * 128;

    const int xi = (mode == 1) ? 1 : (mode == 2) ? 2 : 0;
    const float* Xf = (xi == 0) ? X0 : (xi == 1) ? X1 : X2;
    const float* bias = (mode == 0) ? bq : (mode == 1) ? bk
                       : (mode == 2) ? bv : bg;

    const int t = threadIdx.x, lane = t & 63, wv = t >> 6;   // 8 waves
    const int wm = wv >> 1, wn = wv & 1;                      // 4 x 2
    const int quad = lane >> 4, l15 = lane & 15;

    const short* Wblk = Wsp + (long)mode * 524288 + (long)ntile * 16 * 8192;

    // staging: 24 chunks of 1 KB; wave wv owns chunks wv*3 .. wv*3+2
    // chunks 0-7: X fp32 (per-lane swizzled source); 8-23: W hi/lo bf16
    const int c0 = wv * 3;
    const char* gs[3];
    int gstp[3];
    #pragma unroll
    for (int i = 0; i < 3; ++i) {
        const int c = c0 + i;
        if (c < 8) {
            const int u = c * 64 + lane;        // LDS unit = row*8 + ucol
            const int row = u >> 3, ucol = u & 7;
            gs[i] = (const char*)(Xf + (long)(m0 + row) * 512)
                    + ((ucol ^ (row & 7)) << 4);
            gstp[i] = 128;                      // 32 floats per K-step
        } else {
            gs[i] = (const char*)(Wblk + (c - 8) * 512 + lane * 8);
            gstp[i] = 16384;                    // 8192 shorts per K-step
        }
    }

    auto STAGE = [&](int stg, int ks) {
        char* dstb = (char*)SB + stg * 24576 + c0 * 1024;
        #pragma unroll
        for (int i = 0; i < 3; ++i)
            gload16(gs[i] + (long)ks * gstp[i], dstb + i * 1024);
    };

    // fragment LDS byte offsets (K-step invariant)
    int aoff;
    {
        const int row = wm * 16 + l15;
        aoff = row * 128 + ((quad * 32) ^ ((row & 7) << 4));
    }
    const int sxw = (l15 & 3) << 4;
    int boff[4];
    #pragma unroll
    for (int s2 = 0; s2 < 4; ++s2)
        boff[s2] = 8192 + (wn * 64 + s2 * 16 + l15) * 64 + ((quad * 16) ^ sxw);

    f32x4 acc[4];
    #pragma unroll
    for (int j = 0; j < 4; ++j)
        acc[j] = (f32x4){0.f, 0.f, 0.f, 0.f};

    // prologue: fill stages 0 and 1; wait only for stage 0 (oldest 3)
    STAGE(0, 0);
    STAGE(1, 1);
    asm volatile("s_waitcnt vmcnt(3)" ::: "memory");
    __builtin_amdgcn_s_barrier();

    int cur = 0;
    for (int ks = 0; ks < 16; ++ks) {
        if (ks < 14) {
            int fill = cur + 2; if (fill >= 3) fill -= 3;
            STAGE(fill, ks + 2);
        }
        __builtin_amdgcn_sched_barrier(0);

        const char* stg = (const char*)SB + cur * 24576;
        s16x8 ah, al, bh[4], bl[4];
        {
            f32x4 x0 = *(const f32x4*)(stg + aoff);
            f32x4 x1 = *(const f32x4*)(stg + (aoff ^ 16));
            u32x4 hv, lv;
            #pragma unroll
            for (int j = 0; j < 2; ++j) {
                float a0 = x0[2 * j], b0 = x0[2 * j + 1];
                float a1 = x1[2 * j], b1 = x1[2 * j + 1];
                unsigned h0 = cvtpk(a0, b0);
                unsigned h1 = cvtpk(a1, b1);
                hv[j]     = h0;
                hv[2 + j] = h1;
                float fa0 = __builtin_bit_cast(float, h0 << 16);
                float fb0 = __builtin_bit_cast(float, h0 & 0xFFFF0000u);
                float fa1 = __builtin_bit_cast(float, h1 << 16);
                float fb1 = __builtin_bit_cast(float, h1 & 0xFFFF0000u);
                lv[j]     = cvtpk(a0 - fa0, b0 - fb0);
                lv[2 + j] = cvtpk(a1 - fa1, b1 - fb1);
            }
            ah = __builtin_bit_cast(s16x8, hv);
            al = __builtin_bit_cast(s16x8, lv);
        }
        #pragma unroll
        for (int s2 = 0; s2 < 4; ++s2) {
            bh[s2] = *(const s16x8*)(stg + boff[s2]);
            bl[s2] = *(const s16x8*)(stg + 8192 + boff[s2]);
        }
        __builtin_amdgcn_s_setprio(1);
        #pragma unroll
        for (int j = 0; j < 4; ++j) {
            acc[j] = __builtin_amdgcn_mfma_f32_16x16x32_bf16(ah, bh[j], acc[j], 0, 0, 0);
            acc[j] = __builtin_amdgcn_mfma_f32_16x16x32_bf16(al, bh[j], acc[j], 0, 0, 0);
            acc[j] = __builtin_amdgcn_mfma_f32_16x16x32_bf16(ah, bl[j], acc[j], 0, 0, 0);
        }
        __builtin_amdgcn_s_setprio(0);

        if (ks < 14)       asm volatile("s_waitcnt vmcnt(3)" ::: "memory");
        else if (ks == 14) asm volatile("s_waitcnt vmcnt(0)" ::: "memory");
        __builtin_amdgcn_sched_barrier(0);
        __builtin_amdgcn_s_barrier();

        cur += 1; if (cur >= 3) cur -= 3;
    }

    __syncthreads();   // full drain; LDS reusable by epilogues

    const int bb = m0 >> 11, posb = m0 & 2047;
    const int head = (n0 >> 6) + wn;     // wave covers one full head (64 cols)

    if (mode == 0) {
        short* Thi = SB + wv * 2304;            // 16 x 72
        short* Tlo = Thi + 1152;
        #pragma unroll
        for (int ns = 0; ns < 4; ++ns) {
            const int col = n0 + wn * 64 + ns * 16 + l15;
            const float bvv = bias[col];
            const int pp = (ns * 16 + l15) >> 1;
            #pragma unroll
            for (int r = 0; r < 4; ++r) {
                const int m = m0 + wm * 16 + quad * 4 + r;
                const int pos = m & 2047;
                float x = acc[ns][r] + bvv;
                float prt = __shfl_xor(x, 1);
                float2 sc = SC[pos * 32 + pp];
                float y0 = x * sc.x - prt * sc.y;
                float y1 = prt * sc.x + x * sc.y;
                if (!(l15 & 1)) {
                    short h0 = f2bf(y0), h1 = f2bf(y1);
                    short l0 = f2bf(y0 - bf2f(h0)), l1 = f2bf(y1 - bf2f(h1));
                    const int o = (quad * 4 + r) * 72 + ns * 16 + l15;
                    *(unsigned*)&Thi[o] = pack2(h0, h1);
                    *(unsigned*)&Tlo[o] = pack2(l0, l1);
                }
            }
        }
        #pragma unroll
        for (int p2 = 0; p2 < 2; ++p2) {
            const int row = p2 * 8 + (lane >> 3);
            const int ch = (lane & 7) * 8;
            s16x8 vh = *(const s16x8*)&Thi[row * 72 + ch];
            s16x8 vl = *(const s16x8*)&Tlo[row * 72 + ch];
            const long o = ((long)(bb * 8 + head) * 2048 + posb + wm * 16 + row) * 64 + ch;
            *(s16x8*)(Qh + o) = vh;
            *(s16x8*)(Ql + o) = vl;
        }
    } else if (mode == 1) {
        short* Thi = SB + wv * 1152;            // 16 x 72
        #pragma unroll
        for (int ns = 0; ns < 4; ++ns) {
            const int col = n0 + wn * 64 + ns * 16 + l15;
            const float bvv = bias[col];
            const int pp = (ns * 16 + l15) >> 1;
            #pragma unroll
            for (int r = 0; r < 4; ++r) {
                const int m = m0 + wm * 16 + quad * 4 + r;
                const int pos = m & 2047;
                float x = acc[ns][r] + bvv;
                float prt = __shfl_xor(x, 1);
                float2 sc = SC[pos * 32 + pp];
                float y0 = (x * sc.x - prt * sc.y) * 0.125f;
                float y1 = (prt * sc.x + x * sc.y) * 0.125f;
                if (!(l15 & 1)) {
                    const int o = (quad * 4 + r) * 72 + ns * 16 + l15;
                    *(unsigned*)&Thi[o] = pack2(f2bf(y0), f2bf(y1));
                }
            }
        }
        #pragma unroll
        for (int p2 = 0; p2 < 2; ++p2) {
            const int row = p2 * 8 + (lane >> 3);
            const int ch = (lane & 7) * 8;
            s16x8 vh = *(const s16x8*)&Thi[row * 72 + ch];
            const long o = ((long)(bb * 8 + head) * 2048 + posb + wm * 16 + row) * 64 + ch;
            *(s16x8*)(Kh + o) = vh;
        }
    } else if (mode == 2) {
        short* T2 = SB;   // 128 x 72
        #pragma unroll
        for (int ns = 0; ns < 4; ++ns) {
            const int col = n0 + wn * 64 + ns * 16 + l15;
            const float bvv = bias[col];
            s16x4 pk;
            #pragma unroll
            for (int r = 0; r < 4; ++r)
                pk[r] = f2bf(acc[ns][r] + bvv);
            *(s16x4*)&T2[(wn * 64 + ns * 16 + l15) * 72
                         + wm * 16 + quad * 4] = pk;
        }
        __syncthreads();
        #pragma unroll
        for (int pass = 0; pass < 2; ++pass) {
            const int row = pass * 64 + (t >> 3);    // 0..127
            const int ch = (t & 7) * 8;
            s16x8 v = *(const s16x8*)&T2[row * 72 + ch];
            const int hd = (n0 >> 6) + (row >> 6);
            const int d = row & 63;
            const long o = ((long)(bb * 8 + hd) * 64 + d) * 2048 + posb + ch;
            *(s16x8*)(Vth + o) = v;
        }
    } else {
        #pragma unroll
        for (int ns = 0; ns < 4; ++ns) {
            const int col = n0 + wn * 64 + ns * 16 + l15;
            const float bvv = bias[col];
            #pragma unroll
            for (int r = 0; r < 4; ++r) {
                const int m = m0 + wm * 16 + quad * 4 + r;
                float x = acc[ns][r] + bvv;
                G[(long)m * 512 + col] = x / (1.0f + expf(-x));
            }
        }
    }
}

// ---------------------------------------------------------------------------
// Retention attention, split-K (CHUNK=16), double-buffered K/V LDS, ONE
// barrier/tile, s_setprio around MFMA clusters. Single-chunk pairs
// (c==0 && ntiles<=16) run the epilogue inline; else partials to Racc.
// ---------------------------------------------------------------------------
__global__ __launch_bounds__(256) void attn_chunk_kernel(
    const short* __restrict__ Qh_g, const short* __restrict__ Ql_g,
    const short* __restrict__ Kh_g, const short* __restrict__ Vth_g,
    const float* __restrict__ G, short* __restrict__ RGh,
    float* __restrict__ Racc)
{
    __shared__ __align__(16) short KhS[2][4608], VhS[2][4608];
    __shared__ __align__(16) short PhS[4352];

    const int fid = blockIdx.x;          // 0..1023
    const int bh = fid & 15;
    const int rest = fid >> 4;
    const int qt = rest & 31;
    const int c  = rest >> 5;            // 0..1
    const int h = bh & 7, b = bh >> 3;
    const int n0 = qt * 64;

    float l2g;
    int stLo;
    decay_params(h, n0, l2g, stLo);
    const int ntiles = qt - stLo + 1;
    const int st0 = stLo + c * 16;
    if (st0 > qt) return;
    const int stHi = min(st0 + 15, qt);

    const int t = threadIdx.x, lane = t & 63, wv = t >> 6;
    const int quad = lane >> 4, l15 = lane & 15;
    const long base = (long)bh * 2048 * 64;

    float gneg[16];
    #pragma unroll
    for (int i = 0; i < 16; ++i)
        gneg[i] = exp2f(-(float)((i >> 2) * 16 + (i & 3)) * l2g);

    const int srow = t >> 2;
    const int scol = (t & 3) * 16;
    const int n = n0 + wv * 16 + l15;

    s16x8 qh[2], ql[2];
    {
        const short* qp  = Qh_g + base + (long)(n0 + wv * 16 + l15) * 64 + quad * 8;
        const short* qp2 = Ql_g + base + (long)(n0 + wv * 16 + l15) * 64 + quad * 8;
        qh[0] = *(const s16x8*)qp;
        qh[1] = *(const s16x8*)(qp + 32);
        ql[0] = *(const s16x8*)qp2;
        ql[1] = *(const s16x8*)(qp2 + 32);
    }

    f32x4 racc[4];
    #pragma unroll
    for (int i = 0; i < 4; ++i) racc[i] = (f32x4){0.f, 0.f, 0.f, 0.f};

    // prologue: load tile st0 and write buffer 0
    s16x8 pk0, pk1, pv0, pv1;
    {
        const long ko = base + (long)(st0 * 64 + srow) * 64 + scol;
        pk0 = *(const s16x8*)(Kh_g + ko);
        pk1 = *(const s16x8*)(Kh_g + ko + 8);
        const long vo = base + (long)srow * 2048 + st0 * 64 + scol;
        pv0 = *(const s16x8*)(Vth_g + vo);
        pv1 = *(const s16x8*)(Vth_g + vo + 8);
    }
    *(s16x8*)&KhS[0][srow * 72 + scol]     = pk0;
    *(s16x8*)&KhS[0][srow * 72 + scol + 8] = pk1;
    *(s16x8*)&VhS[0][srow * 72 + scol]     = pv0;
    *(s16x8*)&VhS[0][srow * 72 + scol + 8] = pv1;
    __syncthreads();

    int cur = 0;
    for (int st = st0; st <= stHi; ++st, cur ^= 1) {
        if (st < stHi) {
            const long ko = base + (long)((st + 1) * 64 + srow) * 64 + scol;
            pk0 = *(const s16x8*)(Kh_g + ko);
            pk1 = *(const s16x8*)(Kh_g + ko + 8);
            const long vo = base + (long)srow * 2048 + (st + 1) * 64 + scol;
            pv0 = *(const s16x8*)(Vth_g + vo);
            pv1 = *(const s16x8*)(Vth_g + vo + 8);
        }

        const short* khs = KhS[cur];
        const short* vhs = VhS[cur];
        const int s0 = st * 64;
        const float t0 = exp2f((float)(n - s0 - quad * 4) * l2g);

        #pragma unroll
        for (int sub = 0; sub < 4; ++sub) {
            const int ro = (sub * 16 + l15) * 72 + quad * 8;
            s16x8 kh0 = *(const s16x8*)&khs[ro];
            s16x8 kh1 = *(const s16x8*)&khs[ro + 32];
            f32x4 sacc = (f32x4){0.f, 0.f, 0.f, 0.f};
            __builtin_amdgcn_s_setprio(1);
            sacc = __builtin_amdgcn_mfma_f32_16x16x32_bf16(kh0, qh[0], sacc, 0, 0, 0);
            sacc = __builtin_amdgcn_mfma_f32_16x16x32_bf16(kh1, qh[1], sacc, 0, 0, 0);
            sacc = __builtin_amdgcn_mfma_f32_16x16x32_bf16(kh0, ql[0], sacc, 0, 0, 0);
            sacc = __builtin_amdgcn_mfma_f32_16x16x32_bf16(kh1, ql[1], sacc, 0, 0, 0);
            __builtin_amdgcn_s_setprio(0);

            const int sb = s0 + sub * 16 + quad * 4;
            s16x4 pkh;
            #pragma unroll
            for (int r = 0; r < 4; ++r) {
                const int s = sb + r;
                const float wgt = (n >= s) ? t0 * gneg[sub * 4 + r] : 0.0f;
                pkh[r] = f2bf(sacc[r] * wgt);
            }
            *(s16x4*)&PhS[(wv * 16 + l15) * 68 + sub * 16 + quad * 4] = pkh;
        }

        const int pro = (wv * 16 + l15) * 68 + quad * 8;
        s16x8 ph0 = *(const s16x8*)&PhS[pro];
        s16x8 ph1 = *(const s16x8*)&PhS[pro + 32];
        __builtin_amdgcn_s_setprio(1);
        #pragma unroll
        for (int ds = 0; ds < 4; ++ds) {
            const int ro = (ds * 16 + l15) * 72 + quad * 8;
            s16x8 vh0 = *(const s16x8*)&vhs[ro];
            s16x8 vh1 = *(const s16x8*)&vhs[ro + 32];
            racc[ds] = __builtin_amdgcn_mfma_f32_16x16x32_bf16(ph0, vh0, racc[ds], 0, 0, 0);
            racc[ds] = __builtin_amdgcn_mfma_f32_16x16x32_bf16(ph1, vh1, racc[ds], 0, 0, 0);
        }
        __builtin_amdgcn_s_setprio(0);

        if (st < stHi) {
            short* kd = KhS[cur ^ 1];
            short* vd = VhS[cur ^ 1];
            *(s16x8*)&kd[srow * 72 + scol]     = pk0;
            *(s16x8*)&kd[srow * 72 + scol + 8] = pk1;
            *(s16x8*)&vd[srow * 72 + scol]     = pv0;
            *(s16x8*)&vd[srow * 72 + scol + 8] = pv1;
        }
        __syncthreads();
    }

    if (c == 0 && ntiles <= 16) {
        // fused finisher: groupnorm/gate/pack/store (identical math)
        float mean[4], rstd[4];
        #pragma unroll
        for (int r = 0; r < 4; ++r) {
            float s = racc[0][r] + racc[1][r] + racc[2][r] + racc[3][r];
            s += __shfl_xor(s, 1); s += __shfl_xor(s, 2);
            s += __shfl_xor(s, 4); s += __shfl_xor(s, 8);
            mean[r] = s * (1.0f / 64.0f);
            float vs = 0.f;
            #pragma unroll
            for (int ds = 0; ds < 4; ++ds) {
                float d = racc[ds][r] - mean[r];
                vs += d * d;
            }
            vs += __shfl_xor(vs, 1); vs += __shfl_xor(vs, 2);
            vs += __shfl_xor(vs, 4); vs += __shfl_xor(vs, 8);
            rstd[r] = rsqrtf(vs * (1.0f / 64.0f) + 1e-6f);
        }
        short* rgH = (short*)KhS + wv * 1152;
        #pragma unroll
        for (int ds = 0; ds < 4; ++ds) {
            #pragma unroll
            for (int r = 0; r < 4; ++r) {
                const int nn = n0 + wv * 16 + quad * 4 + r;
                const int d = ds * 16 + l15;
                const long gi = ((long)(b * 2048 + nn)) * 512 + h * 64 + d;
                float rg = (racc[ds][r] - mean[r]) * rstd[r] * G[gi];
                float prt = __shfl_xor(rg, 1);
                if (!(l15 & 1)) {
                    const int o = (quad * 4 + r) * 72 + ds * 16 + l15;
                    *(unsigned*)&rgH[o] = pack2(f2bf(rg), f2bf(prt));
                }
            }
        }
        #pragma unroll
        for (int p2 = 0; p2 < 2; ++p2) {
            const int row = p2 * 8 + (lane >> 3);
            const int ch = (lane & 7) * 8;
            s16x8 vh = *(const s16x8*)&rgH[row * 72 + ch];
            const int nn = n0 + wv * 16 + row;
            const long o = ((long)(b * 2048 + nn)) * 512 + h * 64 + ch;
            *(s16x8*)(RGh + o) = vh;
        }
        return;
    }

    // write partial slice [64 rows][64 cols]
    float* dst = Racc + (long)((bh * 32 + qt) * 2 + c) * 4096;
    #pragma unroll
    for (int ds = 0; ds < 4; ++ds)
        #pragma unroll
        for (int r = 0; r < 4; ++r)
            dst[(wv * 16 + quad * 4 + r) * 64 + ds * 16 + l15] = racc[ds][r];
}

// ---------------------------------------------------------------------------
// Finisher: only for two-chunk pairs (ntiles > 16). Sums 2 partials, then
// the unchanged groupnorm/gate/pack/store epilogue.
// ---------------------------------------------------------------------------
__global__ __launch_bounds__(256) void attn_finish_kernel(
    const float* __restrict__ Racc, const float* __restrict__ G,
    short* __restrict__ RGh)
{
    __shared__ __align__(16) short rgS[4608];

    const int fid = blockIdx.x;          // 0..511
    const int bh = fid & 15;
    const int qt = fid >> 4;
    const int h = bh & 7, b = bh >> 3;
    const int n0 = qt * 64;

    float l2g;
    int stLo;
    decay_params(h, n0, l2g, stLo);
    const int ntiles = qt - stLo + 1;
    if (ntiles <= 16) return;            // handled inline by chunk kernel

    const int t = threadIdx.x, lane = t & 63, wv = t >> 6;
    const int quad = lane >> 4, l15 = lane & 15;

    const float* s0 = Racc + (long)((bh * 32 + qt) * 2) * 4096;
    f32x4 racc[4];
    #pragma unroll
    for (int ds = 0; ds < 4; ++ds)
        #pragma unroll
        for (int r = 0; r < 4; ++r) {
            const int o = (wv * 16 + quad * 4 + r) * 64 + ds * 16 + l15;
            racc[ds][r] = s0[o] + s0[4096 + o];
        }

    float mean[4], rstd[4];
    #pragma unroll
    for (int r = 0; r < 4; ++r) {
        float s = racc[0][r] + racc[1][r] + racc[2][r] + racc[3][r];
        s += __shfl_xor(s, 1); s += __shfl_xor(s, 2);
        s += __shfl_xor(s, 4); s += __shfl_xor(s, 8);
        mean[r] = s * (1.0f / 64.0f);
        float vs = 0.f;
        #pragma unroll
        for (int ds = 0; ds < 4; ++ds) {
            float d = racc[ds][r] - mean[r];
            vs += d * d;
        }
        vs += __shfl_xor(vs, 1); vs += __shfl_xor(vs, 2);
        vs += __shfl_xor(vs, 4); vs += __shfl_xor(vs, 8);
        rstd[r] = rsqrtf(vs * (1.0f / 64.0f) + 1e-6f);
    }

    short* rgH = rgS + wv * 1152;
    #pragma unroll
    for (int ds = 0; ds < 4; ++ds) {
        #pragma unroll
        for (int r = 0; r < 4; ++r) {
            const int nn = n0 + wv * 16 + quad * 4 + r;
            const int d = ds * 16 + l15;
            const long gi = ((long)(b * 2048 + nn)) * 512 + h * 64 + d;
            float rg = (racc[ds][r] - mean[r]) * rstd[r] * G[gi];
            float prt = __shfl_xor(rg, 1);
            if (!(l15 & 1)) {
                const int o = (quad * 4 + r) * 72 + ds * 16 + l15;
                *(unsigned*)&rgH[o] = pack2(f2bf(rg), f2bf(prt));
            }
        }
    }
    __syncthreads();
    #pragma unroll
    for (int p2 = 0; p2 < 2; ++p2) {
        const int row = p2 * 8 + (lane >> 3);
        const int ch = (lane & 7) * 8;
        s16x8 vh = *(const s16x8*)&rgS[(wv * 1152 + row * 72 + ch)];
        const int nn = n0 + wv * 16 + row;
        const long o = ((long)(b * 2048 + nn)) * 512 + h * 64 + ch;
        *(s16x8*)(RGh + o) = vh;
    }
}

// ---------------------------------------------------------------------------
// Output projection: out = RG(bf16) @ Wo^T + bo. 32x128 tile, waves 2x2.
// Double-buffered LDS stages, ONE barrier per K-step; reg loads issued early.
// ---------------------------------------------------------------------------
__global__ __launch_bounds__(256) void projo_kernel(
    const short* __restrict__ RGh, const short* __restrict__ Woh_g,
    const float* __restrict__ bo, float* __restrict__ out)
{
    __shared__ __align__(16) char PB[46080];   // 2 stages x 23040

    const short* Wol_g = Woh_g + 262144;
    const int t = threadIdx.x, lane = t & 63, wv = t >> 6;
    const int wm = wv >> 1, wn = wv & 1;
    const int quad = lane >> 4, l15 = lane & 15;
    const int m0 = blockIdx.y * 32, n0 = blockIdx.x * 128;

    f32x4 acc[4];
    #pragma unroll
    for (int j = 0; j < 4; ++j) acc[j] = (f32x4){0.f, 0.f, 0.f, 0.f};

    const int xrow = t >> 3, xcol = (t & 7) * 4;
    const int wrow = t >> 1, wcol = (t & 1) * 16;
    const long xbase = (long)(m0 + xrow) * 512 + xcol;
    const long wbase = (long)(n0 + wrow) * 512 + wcol;

    s16x4 px;
    s16x8 pw0, pw1, pw2, pw3;
    px  = *(const s16x4*)(RGh + xbase);
    pw0 = *(const s16x8*)(Woh_g + wbase);
    pw1 = *(const s16x8*)(Woh_g + wbase + 8);
    pw2 = *(const s16x8*)(Wol_g + wbase);
    pw3 = *(const s16x8*)(Wol_g + wbase + 8);

    // prologue: write stage 0
    {
        short* XhS = (short*)PB;
        short* WhS = XhS + 1280;
        short* WlS = XhS + 6400;
        *(s16x4*)&XhS[xrow * 40 + xcol]     = px;
        *(s16x8*)&WhS[wrow * 40 + wcol]     = pw0;
        *(s16x8*)&WhS[wrow * 40 + wcol + 8] = pw1;
        *(s16x8*)&WlS[wrow * 40 + wcol]     = pw2;
        *(s16x8*)&WlS[wrow * 40 + wcol + 8] = pw3;
    }
    __syncthreads();

    for (int k0 = 0; k0 < 512; k0 += 32) {
        const int cur = (k0 >> 5) & 1;
        const bool more = (k0 + 32 < 512);
        if (more) {
            const long xo = xbase + k0 + 32;
            const long wo = wbase + k0 + 32;
            px  = *(const s16x4*)(RGh + xo);
            pw0 = *(const s16x8*)(Woh_g + wo);
            pw1 = *(const s16x8*)(Woh_g + wo + 8);
            pw2 = *(const s16x8*)(Wol_g + wo);
            pw3 = *(const s16x8*)(Wol_g + wo + 8);
        }

        const short* XhS = (const short*)(PB + cur * 23040);
        const short* WhS = XhS + 1280;
        const short* WlS = XhS + 6400;
        s16x8 ah, bh[4], bl[4];
        {
            const int ro = (wm * 16 + l15) * 40 + quad * 8;
            ah = *(const s16x8*)&XhS[ro];
        }
        #pragma unroll
        for (int s = 0; s < 4; ++s) {
            const int ro = (wn * 64 + s * 16 + l15) * 40 + quad * 8;
            bh[s] = *(const s16x8*)&WhS[ro];
            bl[s] = *(const s16x8*)&WlS[ro];
        }
        #pragma unroll
        for (int j = 0; j < 4; ++j) {
            acc[j] = __builtin_amdgcn_mfma_f32_16x16x32_bf16(ah, bh[j], acc[j], 0, 0, 0);
            acc[j] = __builtin_amdgcn_mfma_f32_16x16x32_bf16(ah, bl[j], acc[j], 0, 0, 0);
        }

        if (more) {
            short* XhD = (short*)(PB + (cur ^ 1) * 23040);
            short* WhD = XhD + 1280;
            short* WlD = XhD + 6400;
            *(s16x4*)&XhD[xrow * 40 + xcol]     = px;
            *(s16x8*)&WhD[wrow * 40 + wcol]     = pw0;
            *(s16x8*)&WhD[wrow * 40 + wcol + 8] = pw1;
            *(s16x8*)&WlD[wrow * 40 + wcol]     = pw2;
            *(s16x8*)&WlD[wrow * 40 + wcol + 8] = pw3;
        }
        __syncthreads();
    }

    float* T = (float*)PB + wv * 1152;   // 16 x 72 fp32
    #pragma unroll
    for (int ns = 0; ns < 4; ++ns) {
        const int col = n0 + wn * 64 + ns * 16 + l15;
        const float bvv = bo[col];
        #pragma unroll
        for (int r = 0; r < 4; ++r)
            T[(quad * 4 + r) * 72 + ns * 16 + l15] = acc[ns][r] + bvv;
    }
    #pragma unroll
    for (int it = 0; it < 2; ++it) {
        const int row = it * 8 + (lane >> 3);
        const int ch = (lane & 7) * 8;
        f32x4 a = *(const f32x4*)&T[row * 72 + ch];
        f32x4 c = *(const f32x4*)&T[row * 72 + ch + 4];
        const long o = (long)(m0 + wm * 16 + row) * 512 + n0 + wn * 64 + ch;
        *(f32x4*)(out + o) = a;
        *(f32x4*)(out + o + 4) = c;
    }
}

extern "C" void kernel_launch(void* const* d_in, const int* in_sizes, int n_in,
                              void* d_out, int out_size, void* d_ws, size_t ws_size,
                              hipStream_t stream) {
    const float* query = (const float*)d_in[0];
    const float* kin   = (const float*)d_in[1];
    const float* vin   = (const float*)d_in[2];
    const float* Wq = (const float*)d_in[3];
    const float* bq = (const float*)d_in[4];
    const float* Wk = (const float*)d_in[5];
    const float* bk = (const float*)d_in[6];
    const float* Wv = (const float*)d_in[7];
    const float* bv = (const float*)d_in[8];
    const float* Wg = (const float*)d_in[9];
    const float* bg = (const float*)d_in[10];
    const float* Wo = (const float*)d_in[11];
    const float* bo = (const float*)d_in[12];

    short* S = (short*)d_ws;
    const long NE = 2097152;             // 4096*512 elements
    short* WSp = S;                      // 5 MB
    short* Xsp = S + 2621440;            // scratch region (Racc)
    short* Qh  = Xsp + 12582912;
    short* Ql  = Qh + NE;
    short* Kh  = Ql + NE;
    short* Vth = Kh + NE;
    float* G   = (float*)(Vth + NE);     // NE floats
    short* RGh = (short*)(G + NE);
    float2* SC = (float2*)(RGh + NE);    // 2048*32 float2 = 512 KB
    float* Racc = (float*)Xsp;           // 16*32*2*4096 f32 = 16 MB

    presplit_kernel<<<576, 256, 0, stream>>>(
        Wq, Wk, Wv, Wg, Wo, WSp, SC);
    projqkvg_kernel<<<dim3(4, 64, 4), 512, 0, stream>>>(
        query, kin, vin, WSp, bq, bk, bv, bg, SC, Qh, Ql, Kh, Vth, G);
    attn_chunk_kernel<<<1024, 256, 0, stream>>>(
        Qh, Ql, Kh, Vth, G, RGh, Racc);
    attn_finish_kernel<<<512, 256, 0, stream>>>(
        Racc, G, RGh);
    projo_kernel<<<dim3(4, 128), 256, 0, stream>>>(
        RGh, WSp + 4 * 524288, bo, (float*)d_out);
}